// Round 1
// baseline (2767.514 us; speedup 1.0000x reference)
//
#include <hip/hip_runtime.h>

#define BB 8
#define CC 384
#define HWP 50176
#define SS 256
#define MM 65536
#define TOPK 9
#define TK 32

// ---------------- K1: per-batch label counts ----------------
__global__ void k_counts(const int* __restrict__ labels, float* __restrict__ counts) {
    __shared__ unsigned int cnt[SS];
    int b = blockIdx.x;
    int t = threadIdx.x;
    cnt[t] = 0u;
    __syncthreads();
    const int* lb = labels + (size_t)b * HWP;
    for (int p = t; p < HWP; p += 256) {
        atomicAdd(&cnt[lb[p]], 1u);
    }
    __syncthreads();
    counts[b * SS + t] = (float)cnt[t];
}

// ---------------- K2: segment sums (one block per (b,c)) ----------------
__global__ void k_segsum(const float* __restrict__ feats, const int* __restrict__ labels,
                         float* __restrict__ segsum) {
    __shared__ float acc[SS];
    int c = blockIdx.x, b = blockIdx.y;
    int t = threadIdx.x;
    acc[t] = 0.f;
    __syncthreads();
    const float4* f4 = (const float4*)(feats + ((size_t)b * CC + c) * HWP);
    const int4*   l4 = (const int4*)(labels + (size_t)b * HWP);
    for (int p = t; p < HWP / 4; p += 256) {
        float4 v = f4[p];
        int4 li = l4[p];
        atomicAdd(&acc[li.x], v.x);
        atomicAdd(&acc[li.y], v.y);
        atomicAdd(&acc[li.z], v.z);
        atomicAdd(&acc[li.w], v.w);
    }
    __syncthreads();
    segsum[((size_t)b * SS + t) * CC + c] = acc[t];
}

// ---------------- K3: memory-bank row norms (wave per row) ----------------
__global__ void k_ynorm(const float* __restrict__ mb, float* __restrict__ yn) {
    int wave = threadIdx.x >> 6;
    int lane = threadIdx.x & 63;
    int row = blockIdx.x * 4 + wave;
    const float* r = mb + (size_t)row * CC;
    float s = 0.f;
#pragma unroll
    for (int i = 0; i < 6; i++) { float v = r[i * 64 + lane]; s = fmaf(v, v, s); }
#pragma unroll
    for (int m = 32; m; m >>= 1) s += __shfl_xor(s, m);
    if (lane == 0) yn[row] = s;
}

// ---------------- K4: finalize emb (divide by counts) + emb norms ----------------
__global__ void k_embfin(float* __restrict__ emb, const float* __restrict__ counts,
                         float* __restrict__ xn) {
    int i = blockIdx.x;           // b*S+s
    int lane = threadIdx.x;       // 64 threads
    float inv = 1.f / fmaxf(counts[i], 1.f);
    float* e = emb + (size_t)i * CC;
    float s = 0.f;
#pragma unroll
    for (int j = 0; j < 6; j++) {
        float v = e[j * 64 + lane] * inv;
        e[j * 64 + lane] = v;
        s = fmaf(v, v, s);
    }
#pragma unroll
    for (int m = 32; m; m >>= 1) s += __shfl_xor(s, m);
    if (lane == 0) xn[i] = s;
}

// ---------------- K5: fp32 GEMM (2048 x 65536, K=384) + fused min/argmin ----------------
__global__ __launch_bounds__(256) void k_gemm_min(
        const float* __restrict__ emb, const float* __restrict__ mb,
        const float* __restrict__ xn, const float* __restrict__ yn,
        unsigned long long* __restrict__ keys) {
    __shared__ float As[TK][128];
    __shared__ float Bs[TK][128];
    int nb = blockIdx.x;  // 0..511 (bank cols)
    int rb = blockIdx.y;  // 0..15  (emb rows)
    int t = threadIdx.x;
    int tx = t & 15, ty = t >> 4;

    float acc[8][8];
#pragma unroll
    for (int i = 0; i < 8; i++)
#pragma unroll
        for (int j = 0; j < 8; j++) acc[i][j] = 0.f;

    const float* Ab = emb + (size_t)(rb * 128) * CC;
    const float* Bb = mb + (size_t)(nb * 128) * CC;

    for (int kt = 0; kt < CC; kt += TK) {
        __syncthreads();
#pragma unroll
        for (int q = 0; q < 4; q++) {
            int f = t + q * 256;
            int row = f >> 3, k4 = f & 7;
            float4 v = *(const float4*)(Ab + (size_t)row * CC + kt + k4 * 4);
            As[k4 * 4 + 0][row] = v.x; As[k4 * 4 + 1][row] = v.y;
            As[k4 * 4 + 2][row] = v.z; As[k4 * 4 + 3][row] = v.w;
            float4 w = *(const float4*)(Bb + (size_t)row * CC + kt + k4 * 4);
            Bs[k4 * 4 + 0][row] = w.x; Bs[k4 * 4 + 1][row] = w.y;
            Bs[k4 * 4 + 2][row] = w.z; Bs[k4 * 4 + 3][row] = w.w;
        }
        __syncthreads();
#pragma unroll
        for (int kk = 0; kk < TK; kk++) {
            float a[8], bv[8];
#pragma unroll
            for (int i = 0; i < 8; i++) a[i] = As[kk][ty * 8 + i];
#pragma unroll
            for (int j = 0; j < 8; j++) bv[j] = Bs[kk][tx + 16 * j];
#pragma unroll
            for (int i = 0; i < 8; i++)
#pragma unroll
                for (int j = 0; j < 8; j++)
                    acc[i][j] = fmaf(a[i], bv[j], acc[i][j]);
        }
    }

    // epilogue: d^2 = xn - 2*dot + yn, clamp 0, encode (bits<<32)|idx, min-reduce
    float ynj[8];
#pragma unroll
    for (int j = 0; j < 8; j++) ynj[j] = yn[nb * 128 + tx + 16 * j];

#pragma unroll
    for (int i = 0; i < 8; i++) {
        int rg = rb * 128 + ty * 8 + i;
        float xr = xn[rg];
        unsigned long long best = ~0ull;
#pragma unroll
        for (int j = 0; j < 8; j++) {
            int ng = nb * 128 + tx + 16 * j;
            float d2 = fmaxf(xr - 2.f * acc[i][j] + ynj[j], 0.f);
            unsigned long long key =
                ((unsigned long long)__float_as_uint(d2) << 32) | (unsigned)ng;
            best = key < best ? key : best;
        }
#pragma unroll
        for (int m = 1; m < 16; m <<= 1) {
            unsigned long long o = __shfl_xor(best, m);
            best = o < best ? o : best;
        }
        if (tx == 0) atomicMin(keys + rg, best);
    }
}

// ---------------- K6: decode keys -> scores (sqrt), locs ----------------
__global__ void k_decode(const unsigned long long* __restrict__ keys,
                         float* __restrict__ scores, int* __restrict__ locs) {
    int i = blockIdx.x * 256 + threadIdx.x;
    unsigned long long k = keys[i];
    scores[i] = sqrtf(__uint_as_float((unsigned)(k >> 32)));
    locs[i] = (int)(k & 0xffffffffu);
}

// ---------------- K7: per-batch argmax of scores (first max on ties) ----------------
__global__ void k_argmax(const float* __restrict__ scores, const int* __restrict__ locs,
                         int* __restrict__ mp_out, float* __restrict__ sc_out,
                         int* __restrict__ nn_out) {
    __shared__ float sv[256];
    __shared__ int si[256];
    int b = blockIdx.x, t = threadIdx.x;
    sv[t] = scores[b * SS + t];
    si[t] = t;
    __syncthreads();
    for (int s = 128; s; s >>= 1) {
        if (t < s) {
            bool take = (sv[t + s] > sv[t]) || (sv[t + s] == sv[t] && si[t + s] < si[t]);
            if (take) { sv[t] = sv[t + s]; si[t] = si[t + s]; }
        }
        __syncthreads();
    }
    if (t == 0) {
        int mp = si[0];
        mp_out[b] = mp;
        sc_out[b] = sv[0];
        nn_out[b] = locs[b * SS + mp];
    }
}

// ---------------- K8: d_nn = dist(mb[nn[b]], mb[m]) for all b, m ----------------
__global__ void k_dnn(const float* __restrict__ mb, const float* __restrict__ yn,
                      const int* __restrict__ nn, float* __restrict__ dnn) {
    __shared__ float nnf[BB][CC];   // 12 KB
    int t = threadIdx.x;
    for (int i = t; i < BB * CC; i += 256) {
        int bb = i / CC, cc = i % CC;
        nnf[bb][cc] = mb[(size_t)nn[bb] * CC + cc];
    }
    __syncthreads();
    int wave = t >> 6, lane = t & 63;
    int m = blockIdx.x * 4 + wave;
    float accv[BB];
#pragma unroll
    for (int b = 0; b < BB; b++) accv[b] = 0.f;
    const float* r = mb + (size_t)m * CC;
#pragma unroll
    for (int i = 0; i < 6; i++) {
        float v = r[i * 64 + lane];
#pragma unroll
        for (int b = 0; b < BB; b++) accv[b] = fmaf(v, nnf[b][i * 64 + lane], accv[b]);
    }
#pragma unroll
    for (int b = 0; b < BB; b++) {
        float s = accv[b];
#pragma unroll
        for (int mm = 32; mm; mm >>= 1) s += __shfl_xor(s, mm);
        if (lane == 0) {
            float d2 = fmaxf(yn[nn[b]] - 2.f * s + yn[m], 0.f);
            dnn[(size_t)b * MM + m] = sqrtf(d2);
        }
    }
}

// ---------------- K9: top-9 smallest d_nn per batch (lexicographic (d, idx)) ----------------
__global__ void k_top9(const float* __restrict__ dnn, int* __restrict__ sup) {
    __shared__ float sd[256][TOPK];
    __shared__ int sx[256][TOPK];
    int b = blockIdx.x, t = threadIdx.x;
    float ld[TOPK];
    int li[TOPK];
#pragma unroll
    for (int k = 0; k < TOPK; k++) { ld[k] = INFINITY; li[k] = MM; }
    const float* d = dnn + (size_t)b * MM;
    for (int m = t; m < MM; m += 256) {
        float v = d[m];
        if (v < ld[TOPK - 1] || (v == ld[TOPK - 1] && m < li[TOPK - 1])) {
            int k = TOPK - 1;
            while (k > 0 && (v < ld[k - 1] || (v == ld[k - 1] && m < li[k - 1]))) {
                ld[k] = ld[k - 1]; li[k] = li[k - 1]; k--;
            }
            ld[k] = v; li[k] = m;
        }
    }
    for (int k = 0; k < TOPK; k++) { sd[t][k] = ld[k]; sx[t][k] = li[k]; }
    __syncthreads();
    for (int s = 128; s; s >>= 1) {
        if (t < s) {
            float md[TOPK]; int mi[TOPK];
            int p = 0, q = 0;
            for (int k = 0; k < TOPK; k++) {
                float va = sd[t][p], vb = sd[t + s][q];
                int ia = sx[t][p], ib = sx[t + s][q];
                bool ta = (va < vb) || (va == vb && ia < ib);
                if (ta) { md[k] = va; mi[k] = ia; p++; }
                else    { md[k] = vb; mi[k] = ib; q++; }
            }
            for (int k = 0; k < TOPK; k++) { sd[t][k] = md[k]; sx[t][k] = mi[k]; }
        }
        __syncthreads();
    }
    if (t < TOPK) sup[b * TOPK + t] = sx[0][t];
}

// ---------------- K10: d_sup, softmax, pred_score ----------------
__global__ void k_pred(const float* __restrict__ emb, const float* __restrict__ mb,
                       const float* __restrict__ yn, const float* __restrict__ xn,
                       const int* __restrict__ mp, const float* __restrict__ scb,
                       const int* __restrict__ sup, float* __restrict__ outp) {
    __shared__ float ds[TOPK];
    int b = blockIdx.x;
    int t = threadIdx.x;          // 256
    int wave = t >> 6, lane = t & 63;
    int mpb = mp[b];
    const float* mf = emb + ((size_t)b * SS + mpb) * CC;
    float xr = xn[b * SS + mpb];
    for (int k = wave; k < TOPK; k += 4) {
        int sidx = sup[b * TOPK + k];
        const float* sr = mb + (size_t)sidx * CC;
        float s = 0.f;
#pragma unroll
        for (int i = 0; i < 6; i++) s = fmaf(mf[i * 64 + lane], sr[i * 64 + lane], s);
#pragma unroll
        for (int mm = 32; mm; mm >>= 1) s += __shfl_xor(s, mm);
        if (lane == 0) ds[k] = sqrtf(fmaxf(xr - 2.f * s + yn[sidx], 0.f));
    }
    __syncthreads();
    if (t == 0) {
        float mx = ds[0];
        for (int k = 1; k < TOPK; k++) mx = fmaxf(mx, ds[k]);
        float num = expf(ds[0] - mx), den = 0.f;
        for (int k = 0; k < TOPK; k++) den += expf(ds[k] - mx);
        outp[b] = (1.f - num / den) * scb[b];
    }
}

// ---------------- K11: scatter scores -> pixel anomaly map ----------------
__global__ void k_map(const float* __restrict__ scores, const int* __restrict__ labels,
                      float* __restrict__ out) {
    size_t i = (size_t)blockIdx.x * 256 + threadIdx.x;   // over B*HW
    int b = (int)(i / HWP);
    out[i] = scores[b * SS + labels[i]];
}

extern "C" void kernel_launch(void* const* d_in, const int* in_sizes, int n_in,
                              void* d_out, int out_size, void* d_ws, size_t ws_size,
                              hipStream_t stream) {
    const float* feats  = (const float*)d_in[0];
    const int*   labels = (const int*)d_in[1];
    const float* mb     = (const float*)d_in[2];
    float* out = (float*)d_out;

    char* ws = (char*)d_ws;
    size_t o = 0;
    float* emb = (float*)(ws + o);                 o += (size_t)BB * SS * CC * 4;   // 3,145,728
    float* yn  = (float*)(ws + o);                 o += (size_t)MM * 4;             // 262,144
    float* xn  = (float*)(ws + o);                 o += (size_t)BB * SS * 4;        // 8,192
    float* cnt = (float*)(ws + o);                 o += (size_t)BB * SS * 4;        // 8,192
    unsigned long long* keys = (unsigned long long*)(ws + o); o += (size_t)BB * SS * 8; // 16,384
    float* scores = (float*)(ws + o);              o += (size_t)BB * SS * 4;
    int*   locs   = (int*)(ws + o);                o += (size_t)BB * SS * 4;
    int*   mp     = (int*)(ws + o);                o += 64;
    float* scb    = (float*)(ws + o);              o += 64;
    int*   nn     = (int*)(ws + o);                o += 64;
    int*   sup    = (int*)(ws + o);                o += 512;
    float* dnn    = (float*)(ws + o);              o += (size_t)BB * MM * 4;        // 2,097,152

    k_counts<<<BB, 256, 0, stream>>>(labels, cnt);
    k_segsum<<<dim3(CC, BB), 256, 0, stream>>>(feats, labels, emb);
    k_ynorm<<<MM / 4, 256, 0, stream>>>(mb, yn);
    k_embfin<<<BB * SS, 64, 0, stream>>>(emb, cnt, xn);

    hipMemsetAsync(keys, 0xFF, (size_t)BB * SS * 8, stream);

    k_gemm_min<<<dim3(MM / 128, (BB * SS) / 128), 256, 0, stream>>>(emb, mb, xn, yn, keys);
    k_decode<<<BB, 256, 0, stream>>>(keys, scores, locs);
    k_argmax<<<BB, 256, 0, stream>>>(scores, locs, mp, scb, nn);
    k_dnn<<<MM / 4, 256, 0, stream>>>(mb, yn, nn, dnn);
    k_top9<<<BB, 256, 0, stream>>>(dnn, sup);
    k_pred<<<BB, 256, 0, stream>>>(emb, mb, yn, xn, mp, scb, sup, out + (size_t)BB * HWP);
    k_map<<<(BB * HWP) / 256, 256, 0, stream>>>(scores, labels, out);
}

// Round 2
// 1717.817 us; speedup vs baseline: 1.6111x; 1.6111x over previous
//
#include <hip/hip_runtime.h>

#define BB 8
#define CC 384
#define HWP 50176
#define SS 256
#define MM 65536
#define TOPK 9
#define GM 2048          // BB*SS emb rows

typedef __attribute__((ext_vector_type(8))) __bf16 bf16x8;
typedef __attribute__((ext_vector_type(16))) float fx16;

__device__ __forceinline__ unsigned short f2bf_rne(float x) {
    unsigned u = __float_as_uint(x);
    unsigned r = (u + 0x7FFFu + ((u >> 16) & 1u)) >> 16;
    return (unsigned short)r;
}

__device__ __forceinline__ void gl_lds16(const void* g, void* l) {
    auto gp = (const __attribute__((address_space(1))) unsigned int*)g;
    auto lp = (__attribute__((address_space(3))) unsigned int*)l;
    __builtin_amdgcn_global_load_lds(gp, lp, 16, 0, 0);
}

// ---------------- K1: per-batch label counts ----------------
__global__ void k_counts(const int* __restrict__ labels, float* __restrict__ counts) {
    __shared__ unsigned int cnt[SS];
    int b = blockIdx.x, t = threadIdx.x;
    cnt[t] = 0u;
    __syncthreads();
    const int* lb = labels + (size_t)b * HWP;
    for (int p = t; p < HWP; p += 256) atomicAdd(&cnt[lb[p]], 1u);
    __syncthreads();
    counts[b * SS + t] = (float)cnt[t];
}

// ---------------- K2: segment sums, 16-channel groups, labels staged once ----------------
#define PX 3136
__global__ void k_segsum2(const float* __restrict__ feats, const int* __restrict__ labels,
                          float* __restrict__ emb) {
    __shared__ float acc[16][SS];
    __shared__ int lab[PX];
    int chunk = blockIdx.x, cg = blockIdx.y, b = blockIdx.z;
    int t = threadIdx.x;
    for (int i = t; i < 16 * SS; i += 256) ((float*)acc)[i] = 0.f;
    for (int p = t; p < PX; p += 256) lab[p] = labels[(size_t)b * HWP + chunk * PX + p];
    __syncthreads();
    for (int c = 0; c < 16; c++) {
        const float4* f4 = (const float4*)(feats + ((size_t)(b * CC + cg * 16 + c)) * HWP + (size_t)chunk * PX);
        for (int p4 = t; p4 < PX / 4; p4 += 256) {
            float4 v = f4[p4];
            atomicAdd(&acc[c][lab[p4 * 4 + 0]], v.x);
            atomicAdd(&acc[c][lab[p4 * 4 + 1]], v.y);
            atomicAdd(&acc[c][lab[p4 * 4 + 2]], v.z);
            atomicAdd(&acc[c][lab[p4 * 4 + 3]], v.w);
        }
    }
    __syncthreads();
    for (int i = t; i < 16 * SS; i += 256) {
        int c = i & 15, s = i >> 4;
        atomicAdd(&emb[(size_t)(b * SS + s) * CC + cg * 16 + c], acc[c][s]);
    }
}

// ---------------- K3: bank fp32->bf16 + row norms ----------------
__global__ void k_cvtmb(const float* __restrict__ mb, unsigned short* __restrict__ mbh,
                        float* __restrict__ yn) {
    int w = threadIdx.x >> 6, l = threadIdx.x & 63;
    int row = blockIdx.x * 4 + w;
    const float* r = mb + (size_t)row * CC;
    unsigned short* o = mbh + (size_t)row * CC;
    float s = 0.f;
#pragma unroll
    for (int i = 0; i < 6; i++) {
        float v = r[i * 64 + l];
        s = fmaf(v, v, s);
        o[i * 64 + l] = f2bf_rne(v);
    }
#pragma unroll
    for (int m = 32; m; m >>= 1) s += __shfl_xor(s, m);
    if (l == 0) yn[row] = s;
}

__global__ void k_ynorm(const float* __restrict__ mb, float* __restrict__ yn) {
    int w = threadIdx.x >> 6, l = threadIdx.x & 63;
    int row = blockIdx.x * 4 + w;
    const float* r = mb + (size_t)row * CC;
    float s = 0.f;
#pragma unroll
    for (int i = 0; i < 6; i++) { float v = r[i * 64 + l]; s = fmaf(v, v, s); }
#pragma unroll
    for (int m = 32; m; m >>= 1) s += __shfl_xor(s, m);
    if (l == 0) yn[row] = s;
}

// ---------------- K4: finalize emb + norms + bf16 copy ----------------
__global__ void k_embfin(float* __restrict__ emb, const float* __restrict__ counts,
                         float* __restrict__ xn, unsigned short* __restrict__ embh) {
    int i = blockIdx.x, l = threadIdx.x;
    float inv = 1.f / fmaxf(counts[i], 1.f);
    float* e = emb + (size_t)i * CC;
    unsigned short* o = embh + (size_t)i * CC;
    float s = 0.f;
#pragma unroll
    for (int j = 0; j < 6; j++) {
        float v = e[j * 64 + l] * inv;
        e[j * 64 + l] = v;
        o[j * 64 + l] = f2bf_rne(v);
        s = fmaf(v, v, s);
    }
#pragma unroll
    for (int m = 32; m; m >>= 1) s += __shfl_xor(s, m);
    if (l == 0) xn[i] = s;
}

// ---------------- K5: bf16 MFMA GEMM + fused row-min ----------------
template <bool REGB>
__global__ __launch_bounds__(256) void k_gemm(
        const unsigned short* __restrict__ Ah, const unsigned short* __restrict__ Bh,
        const float* __restrict__ Bf,
        const float* __restrict__ xn, const float* __restrict__ yn,
        unsigned long long* __restrict__ partials) {
    __shared__ bf16x8 As[8][128];
    __shared__ bf16x8 Bs[8][128];
    __shared__ unsigned long long rowbest[128];
    int bid = blockIdx.x;
    int swz = (bid & 7) * 1024 + (bid >> 3);
    int rb = swz & 15, nb = swz >> 4;
    int t = threadIdx.x;
    int w = t >> 6, l = t & 63;
    int wm = w & 1, wn = w >> 1;

    if (t < 128) rowbest[t] = ~0ull;

    fx16 acc00, acc01, acc10, acc11;
#pragma unroll
    for (int p = 0; p < 16; p++) { acc00[p] = 0.f; acc01[p] = 0.f; acc10[p] = 0.f; acc11[p] = 0.f; }

    const unsigned short* Abase = Ah + (size_t)(rb * 128) * CC;
    const unsigned short* Bbase = REGB ? nullptr : (Bh + (size_t)(nb * 128) * CC);
    const float* Bfbase = Bf + (size_t)(nb * 128) * CC;

    for (int kt = 0; kt < 6; kt++) {
        int k0 = kt * 64;
#pragma unroll
        for (int q = 0; q < 4; q++) {
            int c = q * 256 + t;
            int r = c & 127, g = c >> 7;
            gl_lds16(Abase + (size_t)r * CC + k0 + g * 8, &As[g][r]);
            if (!REGB) {
                gl_lds16(Bbase + (size_t)r * CC + k0 + g * 8, &Bs[g][r]);
            } else {
                const float* src = Bfbase + (size_t)r * CC + k0 + g * 8;
                float4 v0 = *(const float4*)(src);
                float4 v1 = *(const float4*)(src + 4);
                unsigned short tmp[8];
                tmp[0] = f2bf_rne(v0.x); tmp[1] = f2bf_rne(v0.y);
                tmp[2] = f2bf_rne(v0.z); tmp[3] = f2bf_rne(v0.w);
                tmp[4] = f2bf_rne(v1.x); tmp[5] = f2bf_rne(v1.y);
                tmp[6] = f2bf_rne(v1.z); tmp[7] = f2bf_rne(v1.w);
                Bs[g][r] = *(const bf16x8*)tmp;
            }
        }
        __syncthreads();
#pragma unroll
        for (int s = 0; s < 4; s++) {
            int g = s * 2 + (l >> 5);
            bf16x8 a0 = As[g][wm * 64 + (l & 31)];
            bf16x8 a1 = As[g][wm * 64 + 32 + (l & 31)];
            bf16x8 b0 = Bs[g][wn * 64 + (l & 31)];
            bf16x8 b1 = Bs[g][wn * 64 + 32 + (l & 31)];
            acc00 = __builtin_amdgcn_mfma_f32_32x32x16_bf16(a0, b0, acc00, 0, 0, 0);
            acc01 = __builtin_amdgcn_mfma_f32_32x32x16_bf16(a0, b1, acc01, 0, 0, 0);
            acc10 = __builtin_amdgcn_mfma_f32_32x32x16_bf16(a1, b0, acc10, 0, 0, 0);
            acc11 = __builtin_amdgcn_mfma_f32_32x32x16_bf16(a1, b1, acc11, 0, 0, 0);
        }
        __syncthreads();
    }

    int colg0 = nb * 128 + wn * 64 + (l & 31);
    int colg1 = colg0 + 32;
    float yn0 = yn[colg0], yn1 = yn[colg1];
#pragma unroll
    for (int i = 0; i < 2; i++) {
#pragma unroll
        for (int p = 0; p < 16; p++) {
            float a0v = (i == 0) ? acc00[p] : acc10[p];
            float a1v = (i == 0) ? acc01[p] : acc11[p];
            int rl = i * 32 + (p & 3) + 8 * (p >> 2) + 4 * (l >> 5);
            int grow = rb * 128 + wm * 64 + rl;
            float xr = xn[grow];
            float d0 = fmaxf(xr - 2.f * a0v + yn0, 0.f);
            float d1 = fmaxf(xr - 2.f * a1v + yn1, 0.f);
            unsigned long long k0 = ((unsigned long long)__float_as_uint(d0) << 32) | (unsigned)colg0;
            unsigned long long k1 = ((unsigned long long)__float_as_uint(d1) << 32) | (unsigned)colg1;
            unsigned long long best = k0 < k1 ? k0 : k1;
#pragma unroll
            for (int m = 1; m < 32; m <<= 1) {
                unsigned long long o2 = __shfl_xor(best, m);
                if (o2 < best) best = o2;
            }
            if ((l & 31) == 0) atomicMin(&rowbest[wm * 64 + rl], best);
        }
    }
    __syncthreads();
    if (t < 128) partials[(size_t)nb * GM + rb * 128 + t] = rowbest[t];
}

// ---------------- K6/K7: two-stage min reduction ----------------
__global__ void k_reduce1(const unsigned long long* __restrict__ partials,
                          unsigned long long* __restrict__ partial2) {
    int row = blockIdx.x * 256 + threadIdx.x;
    int ng = blockIdx.y;
    unsigned long long m = ~0ull;
    for (int n = 0; n < 64; n++) {
        unsigned long long v = partials[(size_t)(ng * 64 + n) * GM + row];
        if (v < m) m = v;
    }
    partial2[ng * GM + row] = m;
}

__global__ void k_reduce2(const unsigned long long* __restrict__ partial2,
                          float* __restrict__ scores, int* __restrict__ locs) {
    int row = blockIdx.x * 256 + threadIdx.x;
    unsigned long long m = ~0ull;
    for (int g = 0; g < 8; g++) {
        unsigned long long v = partial2[g * GM + row];
        if (v < m) m = v;
    }
    scores[row] = sqrtf(__uint_as_float((unsigned)(m >> 32)));
    locs[row] = (int)(m & 0xffffffffu);
}

// ---------------- K8: per-batch top-4 candidates ----------------
__global__ void k_cand(const float* __restrict__ scores, int* __restrict__ cand) {
    __shared__ unsigned long long key[256];
    __shared__ unsigned long long red[256];
    int b = blockIdx.x, t = threadIdx.x;
    float sc = scores[b * SS + t];
    key[t] = ((unsigned long long)__float_as_uint(sc) << 32) | (unsigned)(255 - t);
    __syncthreads();
    for (int k = 0; k < 4; k++) {
        red[t] = key[t];
        __syncthreads();
        for (int s = 128; s; s >>= 1) {
            if (t < s && red[t + s] > red[t]) red[t] = red[t + s];
            __syncthreads();
        }
        unsigned long long win = red[0];
        int patch = 255 - (int)(win & 0xffffffffu);
        if (t == 0) cand[b * 4 + k] = b * SS + patch;
        __syncthreads();
        if (t == patch) key[t] = 0;
        __syncthreads();
    }
}

// ---------------- K9: exact fp32 re-search for 32 candidate rows ----------------
#define RF_ROWS 8
__global__ __launch_bounds__(256) void k_refine(
        const float* __restrict__ emb, const float* __restrict__ mb,
        const float* __restrict__ xn, const float* __restrict__ yn,
        const int* __restrict__ cand, unsigned long long* __restrict__ refpart) {
    __shared__ float cl[32 * CC];
    __shared__ float xnc[32];
    __shared__ int cr[32];
    __shared__ unsigned long long bmin[32];
    int t = threadIdx.x;
    if (t < 32) cr[t] = cand[t];
    __syncthreads();
    if (t < 32) { xnc[t] = xn[cr[t]]; bmin[t] = ~0ull; }
    for (int i = t; i < 32 * CC; i += 256) {
        int j = i / CC, p = i - j * CC;
        cl[i] = emb[(size_t)cr[j] * CC + p];
    }
    __syncthreads();
    int w = t >> 6, l = t & 63;
    int m0 = blockIdx.x * RF_ROWS + w * 2, m1 = m0 + 1;
    float2 r0[3], r1[3];
#pragma unroll
    for (int c = 0; c < 3; c++) {
        r0[c] = *(const float2*)&mb[(size_t)m0 * CC + c * 128 + l * 2];
        r1[c] = *(const float2*)&mb[(size_t)m1 * CC + c * 128 + l * 2];
    }
    float ya = yn[m0], yb = yn[m1];
    for (int j = 0; j < 32; j++) {
        float s0 = 0.f, s1 = 0.f;
#pragma unroll
        for (int c = 0; c < 3; c++) {
            float2 cv = *(const float2*)&cl[j * CC + c * 128 + l * 2];
            s0 = fmaf(r0[c].x, cv.x, s0); s0 = fmaf(r0[c].y, cv.y, s0);
            s1 = fmaf(r1[c].x, cv.x, s1); s1 = fmaf(r1[c].y, cv.y, s1);
        }
#pragma unroll
        for (int mm = 32; mm; mm >>= 1) { s0 += __shfl_xor(s0, mm); s1 += __shfl_xor(s1, mm); }
        if (l == 0) {
            float d0 = fmaxf(xnc[j] - 2.f * s0 + ya, 0.f);
            float d1 = fmaxf(xnc[j] - 2.f * s1 + yb, 0.f);
            unsigned long long k0 = ((unsigned long long)__float_as_uint(d0) << 32) | (unsigned)m0;
            unsigned long long k1 = ((unsigned long long)__float_as_uint(d1) << 32) | (unsigned)m1;
            unsigned long long kb = k0 < k1 ? k0 : k1;
            atomicMin(&bmin[j], kb);
        }
    }
    __syncthreads();
    if (t < 32) refpart[(size_t)blockIdx.x * 32 + t] = bmin[t];
}

__global__ void k_refred(const unsigned long long* __restrict__ refpart,
                         unsigned long long* __restrict__ keys2) {
    __shared__ unsigned long long red[256];
    int j = blockIdx.x, t = threadIdx.x;
    unsigned long long m = ~0ull;
    for (int i = t; i < MM / RF_ROWS; i += 256) {
        unsigned long long v = refpart[(size_t)i * 32 + j];
        if (v < m) m = v;
    }
    red[t] = m;
    __syncthreads();
    for (int s = 128; s; s >>= 1) {
        if (t < s && red[t + s] < red[t]) red[t] = red[t + s];
        __syncthreads();
    }
    if (t == 0) keys2[j] = red[0];
}

__global__ void k_final(const unsigned long long* __restrict__ keys2, const int* __restrict__ cand,
                        int* __restrict__ mp, float* __restrict__ scb, int* __restrict__ nn) {
    int b = threadIdx.x;
    if (b < BB) {
        float bestsc = -1.f;
        int bestpatch = 1 << 20, bestnn = 0;
        for (int k = 0; k < 4; k++) {
            unsigned long long key = keys2[b * 4 + k];
            float sc = sqrtf(__uint_as_float((unsigned)(key >> 32)));
            int patch = cand[b * 4 + k] & 255;
            int nnidx = (int)(key & 0xffffffffu);
            if (sc > bestsc || (sc == bestsc && patch < bestpatch)) {
                bestsc = sc; bestpatch = patch; bestnn = nnidx;
            }
        }
        mp[b] = bestpatch; scb[b] = bestsc; nn[b] = bestnn;
    }
}

// ---------------- K12: d_nn ----------------
__global__ void k_dnn(const float* __restrict__ mb, const float* __restrict__ yn,
                      const int* __restrict__ nn, float* __restrict__ dnn) {
    __shared__ float nnf[BB][CC];
    int t = threadIdx.x;
    for (int i = t; i < BB * CC; i += 256) {
        int bb = i / CC, cc = i % CC;
        nnf[bb][cc] = mb[(size_t)nn[bb] * CC + cc];
    }
    __syncthreads();
    int w = t >> 6, l = t & 63;
    int m = blockIdx.x * 4 + w;
    float accv[BB];
#pragma unroll
    for (int b = 0; b < BB; b++) accv[b] = 0.f;
    const float* r = mb + (size_t)m * CC;
#pragma unroll
    for (int i = 0; i < 6; i++) {
        float v = r[i * 64 + l];
#pragma unroll
        for (int b = 0; b < BB; b++) accv[b] = fmaf(v, nnf[b][i * 64 + l], accv[b]);
    }
#pragma unroll
    for (int b = 0; b < BB; b++) {
        float s = accv[b];
#pragma unroll
        for (int mm = 32; mm; mm >>= 1) s += __shfl_xor(s, mm);
        if (l == 0) {
            float d2 = fmaxf(yn[nn[b]] - 2.f * s + yn[m], 0.f);
            dnn[(size_t)b * MM + m] = sqrtf(d2);
        }
    }
}

// ---------------- K13: top-9 ----------------
__global__ void k_top9(const float* __restrict__ dnn, int* __restrict__ sup) {
    __shared__ float sd[256][TOPK];
    __shared__ int sx[256][TOPK];
    int b = blockIdx.x, t = threadIdx.x;
    float ld[TOPK];
    int li[TOPK];
#pragma unroll
    for (int k = 0; k < TOPK; k++) { ld[k] = INFINITY; li[k] = MM; }
    const float* d = dnn + (size_t)b * MM;
    for (int m = t; m < MM; m += 256) {
        float v = d[m];
        if (v < ld[TOPK - 1] || (v == ld[TOPK - 1] && m < li[TOPK - 1])) {
            int k = TOPK - 1;
            while (k > 0 && (v < ld[k - 1] || (v == ld[k - 1] && m < li[k - 1]))) {
                ld[k] = ld[k - 1]; li[k] = li[k - 1]; k--;
            }
            ld[k] = v; li[k] = m;
        }
    }
    for (int k = 0; k < TOPK; k++) { sd[t][k] = ld[k]; sx[t][k] = li[k]; }
    __syncthreads();
    for (int s = 128; s; s >>= 1) {
        if (t < s) {
            float md[TOPK]; int mi[TOPK];
            int p = 0, q = 0;
            for (int k = 0; k < TOPK; k++) {
                float va = sd[t][p], vb = sd[t + s][q];
                int ia = sx[t][p], ib = sx[t + s][q];
                bool ta = (va < vb) || (va == vb && ia < ib);
                if (ta) { md[k] = va; mi[k] = ia; p++; }
                else    { md[k] = vb; mi[k] = ib; q++; }
            }
            for (int k = 0; k < TOPK; k++) { sd[t][k] = md[k]; sx[t][k] = mi[k]; }
        }
        __syncthreads();
    }
    if (t < TOPK) sup[b * TOPK + t] = sx[0][t];
}

// ---------------- K14: pred_score ----------------
__global__ void k_pred(const float* __restrict__ emb, const float* __restrict__ mb,
                       const float* __restrict__ yn, const float* __restrict__ xn,
                       const int* __restrict__ mp, const float* __restrict__ scb,
                       const int* __restrict__ sup, float* __restrict__ outp) {
    __shared__ float ds[TOPK];
    int b = blockIdx.x;
    int t = threadIdx.x;
    int w = t >> 6, l = t & 63;
    int mpb = mp[b];
    const float* mf = emb + ((size_t)b * SS + mpb) * CC;
    float xr = xn[b * SS + mpb];
    for (int k = w; k < TOPK; k += 4) {
        int sidx = sup[b * TOPK + k];
        const float* sr = mb + (size_t)sidx * CC;
        float s = 0.f;
#pragma unroll
        for (int i = 0; i < 6; i++) s = fmaf(mf[i * 64 + l], sr[i * 64 + l], s);
#pragma unroll
        for (int mm = 32; mm; mm >>= 1) s += __shfl_xor(s, mm);
        if (l == 0) ds[k] = sqrtf(fmaxf(xr - 2.f * s + yn[sidx], 0.f));
    }
    __syncthreads();
    if (t == 0) {
        float mx = ds[0];
        for (int k = 1; k < TOPK; k++) mx = fmaxf(mx, ds[k]);
        float num = expf(ds[0] - mx), den = 0.f;
        for (int k = 0; k < TOPK; k++) den += expf(ds[k] - mx);
        outp[b] = (1.f - num / den) * scb[b];
    }
}

// ---------------- K15: anomaly map scatter ----------------
__global__ void k_map(const float* __restrict__ scores, const int* __restrict__ labels,
                      float* __restrict__ out) {
    size_t i = (size_t)blockIdx.x * 256 + threadIdx.x;
    int b = (int)(i / HWP);
    out[i] = scores[b * SS + labels[i]];
}

extern "C" void kernel_launch(void* const* d_in, const int* in_sizes, int n_in,
                              void* d_out, int out_size, void* d_ws, size_t ws_size,
                              hipStream_t stream) {
    const float* feats  = (const float*)d_in[0];
    const int*   labels = (const int*)d_in[1];
    const float* mb     = (const float*)d_in[2];
    float* out = (float*)d_out;

    char* ws = (char*)d_ws;
    const size_t SZ_MBH   = (size_t)MM * CC * 2;
    const size_t SZ_EMBH  = (size_t)GM * CC * 2;
    const size_t SZ_EMB   = (size_t)GM * CC * 4;
    const size_t SZ_YN    = (size_t)MM * 4;
    const size_t SZ_SMALL = 8192;
    const size_t SZ_P2    = (size_t)8 * GM * 8;
    const size_t SZ_BIG   = (size_t)512 * GM * 8;

    size_t need_full = SZ_MBH + SZ_EMBH + SZ_EMB + SZ_YN + 4 * SZ_SMALL + 2048 + SZ_P2 + SZ_BIG + 512;
    bool lowmem = ws_size < need_full;

    size_t o = 0;
    unsigned short* mbh = nullptr;
    if (!lowmem) { mbh = (unsigned short*)(ws + o); o += SZ_MBH; }
    unsigned short* embh = (unsigned short*)(ws + o); o += SZ_EMBH;
    float* emb = (float*)(ws + o);                    o += SZ_EMB;
    float* yn  = (float*)(ws + o);                    o += SZ_YN;
    float* xn  = (float*)(ws + o);                    o += SZ_SMALL;
    float* cnt = (float*)(ws + o);                    o += SZ_SMALL;
    float* scores = (float*)(ws + o);                 o += SZ_SMALL;
    int*   locs   = (int*)(ws + o);                   o += SZ_SMALL;
    int*   cand   = (int*)(ws + o);                   o += 256;
    unsigned long long* keys2 = (unsigned long long*)(ws + o); o += 256;
    int*   mp  = (int*)(ws + o);                      o += 128;
    float* scb = (float*)(ws + o);                    o += 128;
    int*   nn  = (int*)(ws + o);                      o += 128;
    int*   sup = (int*)(ws + o);                      o += 512;
    o = (o + 255) & ~(size_t)255;
    unsigned long long* partial2 = (unsigned long long*)(ws + o); o += SZ_P2;
    char* big = ws + o;
    unsigned long long* partials = (unsigned long long*)big;
    unsigned long long* refpart  = (unsigned long long*)big;   // reused after partials consumed
    float* dnn = (float*)(big + 4194304);

    hipMemsetAsync(emb, 0, SZ_EMB, stream);
    k_counts<<<BB, 256, 0, stream>>>(labels, cnt);
    k_segsum2<<<dim3(16, 24, BB), 256, 0, stream>>>(feats, labels, emb);
    if (!lowmem) k_cvtmb<<<MM / 4, 256, 0, stream>>>(mb, mbh, yn);
    else         k_ynorm<<<MM / 4, 256, 0, stream>>>(mb, yn);
    k_embfin<<<GM, 64, 0, stream>>>(emb, cnt, xn, embh);

    if (!lowmem)
        k_gemm<false><<<8192, 256, 0, stream>>>(embh, mbh, mb, xn, yn, partials);
    else
        k_gemm<true><<<8192, 256, 0, stream>>>(embh, embh, mb, xn, yn, partials);

    k_reduce1<<<dim3(8, 8), 256, 0, stream>>>(partials, partial2);
    k_reduce2<<<8, 256, 0, stream>>>(partial2, scores, locs);
    k_cand<<<BB, 256, 0, stream>>>(scores, cand);
    k_refine<<<MM / RF_ROWS, 256, 0, stream>>>(emb, mb, xn, yn, cand, refpart);
    k_refred<<<32, 256, 0, stream>>>(refpart, keys2);
    k_final<<<1, 64, 0, stream>>>(keys2, cand, mp, scb, nn);
    k_dnn<<<MM / 4, 256, 0, stream>>>(mb, yn, nn, dnn);
    k_top9<<<BB, 256, 0, stream>>>(dnn, sup);
    k_pred<<<BB, 256, 0, stream>>>(emb, mb, yn, xn, mp, scb, sup, out + (size_t)BB * HWP);
    k_map<<<(BB * HWP) / 256, 256, 0, stream>>>(scores, labels, out);
}

// Round 3
// 1688.951 us; speedup vs baseline: 1.6386x; 1.0171x over previous
//
#include <hip/hip_runtime.h>

#define BB 8
#define CC 384
#define HWP 50176
#define SS 256
#define MM 65536
#define TOPK 9
#define GM 2048          // BB*SS emb rows

typedef __attribute__((ext_vector_type(8))) __bf16 bf16x8;
typedef __attribute__((ext_vector_type(16))) float fx16;

__device__ __forceinline__ unsigned short f2bf_rne(float x) {
    unsigned u = __float_as_uint(x);
    unsigned r = (u + 0x7FFFu + ((u >> 16) & 1u)) >> 16;
    return (unsigned short)r;
}

__device__ __forceinline__ void gl_lds16(const void* g, void* l) {
    auto gp = (const __attribute__((address_space(1))) unsigned int*)g;
    auto lp = (__attribute__((address_space(3))) unsigned int*)l;
    __builtin_amdgcn_global_load_lds(gp, lp, 16, 0, 0);
}

// ---------------- K1: per-batch label counts ----------------
__global__ void k_counts(const int* __restrict__ labels, float* __restrict__ counts) {
    __shared__ unsigned int cnt[SS];
    int b = blockIdx.x, t = threadIdx.x;
    cnt[t] = 0u;
    __syncthreads();
    const int* lb = labels + (size_t)b * HWP;
    for (int p = t; p < HWP; p += 256) atomicAdd(&cnt[lb[p]], 1u);
    __syncthreads();
    counts[b * SS + t] = (float)cnt[t];
}

// ---------------- K2: segment sums, channel-batched loads for MLP ----------------
// grid (chunk=16, cgrp=24, b=8); block 256. 16 channels per block.
// Key: per pixel-group, issue label int4 + 16 independent channel float4 loads
// BEFORE any LDS atomic -> 16 loads in flight per wave (was 1).
#define PX 3136
__global__ __launch_bounds__(256) void k_segsum3(const float* __restrict__ feats,
                                                 const int* __restrict__ labels,
                                                 float* __restrict__ emb) {
    __shared__ float acc[16][SS];   // 16 KB
    int chunk = blockIdx.x, cg = blockIdx.y, b = blockIdx.z;
    int t = threadIdx.x;
    for (int i = t; i < 16 * SS; i += 256) ((float*)acc)[i] = 0.f;
    __syncthreads();

    const int4* l4 = (const int4*)(labels + (size_t)b * HWP + (size_t)chunk * PX);
    const float4* f4 = (const float4*)(feats + ((size_t)(b * CC + cg * 16)) * HWP + (size_t)chunk * PX);
    const int CS4 = HWP / 4;  // float4 channel stride

#pragma unroll
    for (int j = 0; j < 4; j++) {
        int p4 = j * 256 + t;
        if (p4 < PX / 4) {
            int4 li = l4[p4];
            float4 v[16];
#pragma unroll
            for (int c = 0; c < 16; c++) v[c] = f4[(size_t)c * CS4 + p4];
#pragma unroll
            for (int c = 0; c < 16; c++) {
                atomicAdd(&acc[c][li.x], v[c].x);
                atomicAdd(&acc[c][li.y], v[c].y);
                atomicAdd(&acc[c][li.z], v[c].z);
                atomicAdd(&acc[c][li.w], v[c].w);
            }
        }
    }
    __syncthreads();
    for (int i = t; i < 16 * SS; i += 256) {
        int c = i & 15, s = i >> 4;
        atomicAdd(&emb[(size_t)(b * SS + s) * CC + cg * 16 + c], acc[c][s]);
    }
}

// ---------------- K3: bank fp32->bf16 + row norms ----------------
__global__ void k_cvtmb(const float* __restrict__ mb, unsigned short* __restrict__ mbh,
                        float* __restrict__ yn) {
    int w = threadIdx.x >> 6, l = threadIdx.x & 63;
    int row = blockIdx.x * 4 + w;
    const float* r = mb + (size_t)row * CC;
    unsigned short* o = mbh + (size_t)row * CC;
    float s = 0.f;
#pragma unroll
    for (int i = 0; i < 6; i++) {
        float v = r[i * 64 + l];
        s = fmaf(v, v, s);
        o[i * 64 + l] = f2bf_rne(v);
    }
#pragma unroll
    for (int m = 32; m; m >>= 1) s += __shfl_xor(s, m);
    if (l == 0) yn[row] = s;
}

__global__ void k_ynorm(const float* __restrict__ mb, float* __restrict__ yn) {
    int w = threadIdx.x >> 6, l = threadIdx.x & 63;
    int row = blockIdx.x * 4 + w;
    const float* r = mb + (size_t)row * CC;
    float s = 0.f;
#pragma unroll
    for (int i = 0; i < 6; i++) { float v = r[i * 64 + l]; s = fmaf(v, v, s); }
#pragma unroll
    for (int m = 32; m; m >>= 1) s += __shfl_xor(s, m);
    if (l == 0) yn[row] = s;
}

// ---------------- K4: finalize emb + norms + bf16 copy ----------------
__global__ void k_embfin(float* __restrict__ emb, const float* __restrict__ counts,
                         float* __restrict__ xn, unsigned short* __restrict__ embh) {
    int i = blockIdx.x, l = threadIdx.x;
    float inv = 1.f / fmaxf(counts[i], 1.f);
    float* e = emb + (size_t)i * CC;
    unsigned short* o = embh + (size_t)i * CC;
    float s = 0.f;
#pragma unroll
    for (int j = 0; j < 6; j++) {
        float v = e[j * 64 + l] * inv;
        e[j * 64 + l] = v;
        o[j * 64 + l] = f2bf_rne(v);
        s = fmaf(v, v, s);
    }
#pragma unroll
    for (int m = 32; m; m >>= 1) s += __shfl_xor(s, m);
    if (l == 0) xn[i] = s;
}

// ---------------- K5: bf16 MFMA GEMM + fused row-min ----------------
template <bool REGB>
__global__ __launch_bounds__(256) void k_gemm(
        const unsigned short* __restrict__ Ah, const unsigned short* __restrict__ Bh,
        const float* __restrict__ Bf,
        const float* __restrict__ xn, const float* __restrict__ yn,
        unsigned long long* __restrict__ partials) {
    __shared__ bf16x8 As[8][128];
    __shared__ bf16x8 Bs[8][128];
    __shared__ unsigned long long rowbest[128];
    int bid = blockIdx.x;
    int swz = (bid & 7) * 1024 + (bid >> 3);
    int rb = swz & 15, nb = swz >> 4;
    int t = threadIdx.x;
    int w = t >> 6, l = t & 63;
    int wm = w & 1, wn = w >> 1;

    if (t < 128) rowbest[t] = ~0ull;

    fx16 acc00, acc01, acc10, acc11;
#pragma unroll
    for (int p = 0; p < 16; p++) { acc00[p] = 0.f; acc01[p] = 0.f; acc10[p] = 0.f; acc11[p] = 0.f; }

    const unsigned short* Abase = Ah + (size_t)(rb * 128) * CC;
    const unsigned short* Bbase = REGB ? nullptr : (Bh + (size_t)(nb * 128) * CC);
    const float* Bfbase = Bf + (size_t)(nb * 128) * CC;

    for (int kt = 0; kt < 6; kt++) {
        int k0 = kt * 64;
#pragma unroll
        for (int q = 0; q < 4; q++) {
            int c = q * 256 + t;
            int r = c & 127, g = c >> 7;
            gl_lds16(Abase + (size_t)r * CC + k0 + g * 8, &As[g][r]);
            if (!REGB) {
                gl_lds16(Bbase + (size_t)r * CC + k0 + g * 8, &Bs[g][r]);
            } else {
                const float* src = Bfbase + (size_t)r * CC + k0 + g * 8;
                float4 v0 = *(const float4*)(src);
                float4 v1 = *(const float4*)(src + 4);
                unsigned short tmp[8];
                tmp[0] = f2bf_rne(v0.x); tmp[1] = f2bf_rne(v0.y);
                tmp[2] = f2bf_rne(v0.z); tmp[3] = f2bf_rne(v0.w);
                tmp[4] = f2bf_rne(v1.x); tmp[5] = f2bf_rne(v1.y);
                tmp[6] = f2bf_rne(v1.z); tmp[7] = f2bf_rne(v1.w);
                Bs[g][r] = *(const bf16x8*)tmp;
            }
        }
        __syncthreads();
#pragma unroll
        for (int s = 0; s < 4; s++) {
            int g = s * 2 + (l >> 5);
            bf16x8 a0 = As[g][wm * 64 + (l & 31)];
            bf16x8 a1 = As[g][wm * 64 + 32 + (l & 31)];
            bf16x8 b0 = Bs[g][wn * 64 + (l & 31)];
            bf16x8 b1 = Bs[g][wn * 64 + 32 + (l & 31)];
            acc00 = __builtin_amdgcn_mfma_f32_32x32x16_bf16(a0, b0, acc00, 0, 0, 0);
            acc01 = __builtin_amdgcn_mfma_f32_32x32x16_bf16(a0, b1, acc01, 0, 0, 0);
            acc10 = __builtin_amdgcn_mfma_f32_32x32x16_bf16(a1, b0, acc10, 0, 0, 0);
            acc11 = __builtin_amdgcn_mfma_f32_32x32x16_bf16(a1, b1, acc11, 0, 0, 0);
        }
        __syncthreads();
    }

    int colg0 = nb * 128 + wn * 64 + (l & 31);
    int colg1 = colg0 + 32;
    float yn0 = yn[colg0], yn1 = yn[colg1];
#pragma unroll
    for (int i = 0; i < 2; i++) {
#pragma unroll
        for (int p = 0; p < 16; p++) {
            float a0v = (i == 0) ? acc00[p] : acc10[p];
            float a1v = (i == 0) ? acc01[p] : acc11[p];
            int rl = i * 32 + (p & 3) + 8 * (p >> 2) + 4 * (l >> 5);
            int grow = rb * 128 + wm * 64 + rl;
            float xr = xn[grow];
            float d0 = fmaxf(xr - 2.f * a0v + yn0, 0.f);
            float d1 = fmaxf(xr - 2.f * a1v + yn1, 0.f);
            unsigned long long k0 = ((unsigned long long)__float_as_uint(d0) << 32) | (unsigned)colg0;
            unsigned long long k1 = ((unsigned long long)__float_as_uint(d1) << 32) | (unsigned)colg1;
            unsigned long long best = k0 < k1 ? k0 : k1;
#pragma unroll
            for (int m = 1; m < 32; m <<= 1) {
                unsigned long long o2 = __shfl_xor(best, m);
                if (o2 < best) best = o2;
            }
            if ((l & 31) == 0) atomicMin(&rowbest[wm * 64 + rl], best);
        }
    }
    __syncthreads();
    if (t < 128) partials[(size_t)nb * GM + rb * 128 + t] = rowbest[t];
}

// ---------------- K6/K7: two-stage min reduction ----------------
__global__ void k_reduce1(const unsigned long long* __restrict__ partials,
                          unsigned long long* __restrict__ partial2) {
    int row = blockIdx.x * 256 + threadIdx.x;
    int ng = blockIdx.y;
    unsigned long long m = ~0ull;
    for (int n = 0; n < 64; n++) {
        unsigned long long v = partials[(size_t)(ng * 64 + n) * GM + row];
        if (v < m) m = v;
    }
    partial2[ng * GM + row] = m;
}

__global__ void k_reduce2(const unsigned long long* __restrict__ partial2,
                          float* __restrict__ scores, int* __restrict__ locs) {
    int row = blockIdx.x * 256 + threadIdx.x;
    unsigned long long m = ~0ull;
    for (int g = 0; g < 8; g++) {
        unsigned long long v = partial2[g * GM + row];
        if (v < m) m = v;
    }
    scores[row] = sqrtf(__uint_as_float((unsigned)(m >> 32)));
    locs[row] = (int)(m & 0xffffffffu);
}

// ---------------- K8: per-batch top-4 candidates ----------------
__global__ void k_cand(const float* __restrict__ scores, int* __restrict__ cand) {
    __shared__ unsigned long long key[256];
    __shared__ unsigned long long red[256];
    int b = blockIdx.x, t = threadIdx.x;
    float sc = scores[b * SS + t];
    key[t] = ((unsigned long long)__float_as_uint(sc) << 32) | (unsigned)(255 - t);
    __syncthreads();
    for (int k = 0; k < 4; k++) {
        red[t] = key[t];
        __syncthreads();
        for (int s = 128; s; s >>= 1) {
            if (t < s && red[t + s] > red[t]) red[t] = red[t + s];
            __syncthreads();
        }
        unsigned long long win = red[0];
        int patch = 255 - (int)(win & 0xffffffffu);
        if (t == 0) cand[b * 4 + k] = b * SS + patch;
        __syncthreads();
        if (t == patch) key[t] = 0;
        __syncthreads();
    }
}

// ---------------- K9: exact fp32 re-search for 32 candidate rows ----------------
#define RF_ROWS 8
__global__ __launch_bounds__(256) void k_refine(
        const float* __restrict__ emb, const float* __restrict__ mb,
        const float* __restrict__ xn, const float* __restrict__ yn,
        const int* __restrict__ cand, unsigned long long* __restrict__ refpart) {
    __shared__ float cl[32 * CC];
    __shared__ float xnc[32];
    __shared__ int cr[32];
    __shared__ unsigned long long bmin[32];
    int t = threadIdx.x;
    if (t < 32) cr[t] = cand[t];
    __syncthreads();
    if (t < 32) { xnc[t] = xn[cr[t]]; bmin[t] = ~0ull; }
    for (int i = t; i < 32 * CC; i += 256) {
        int j = i / CC, p = i - j * CC;
        cl[i] = emb[(size_t)cr[j] * CC + p];
    }
    __syncthreads();
    int w = t >> 6, l = t & 63;
    int m0 = blockIdx.x * RF_ROWS + w * 2, m1 = m0 + 1;
    float2 r0[3], r1[3];
#pragma unroll
    for (int c = 0; c < 3; c++) {
        r0[c] = *(const float2*)&mb[(size_t)m0 * CC + c * 128 + l * 2];
        r1[c] = *(const float2*)&mb[(size_t)m1 * CC + c * 128 + l * 2];
    }
    float ya = yn[m0], yb = yn[m1];
    for (int j = 0; j < 32; j++) {
        float s0 = 0.f, s1 = 0.f;
#pragma unroll
        for (int c = 0; c < 3; c++) {
            float2 cv = *(const float2*)&cl[j * CC + c * 128 + l * 2];
            s0 = fmaf(r0[c].x, cv.x, s0); s0 = fmaf(r0[c].y, cv.y, s0);
            s1 = fmaf(r1[c].x, cv.x, s1); s1 = fmaf(r1[c].y, cv.y, s1);
        }
#pragma unroll
        for (int mm = 32; mm; mm >>= 1) { s0 += __shfl_xor(s0, mm); s1 += __shfl_xor(s1, mm); }
        if (l == 0) {
            float d0 = fmaxf(xnc[j] - 2.f * s0 + ya, 0.f);
            float d1 = fmaxf(xnc[j] - 2.f * s1 + yb, 0.f);
            unsigned long long k0 = ((unsigned long long)__float_as_uint(d0) << 32) | (unsigned)m0;
            unsigned long long k1 = ((unsigned long long)__float_as_uint(d1) << 32) | (unsigned)m1;
            unsigned long long kb = k0 < k1 ? k0 : k1;
            atomicMin(&bmin[j], kb);
        }
    }
    __syncthreads();
    if (t < 32) refpart[(size_t)blockIdx.x * 32 + t] = bmin[t];
}

__global__ void k_refred(const unsigned long long* __restrict__ refpart,
                         unsigned long long* __restrict__ keys2) {
    __shared__ unsigned long long red[256];
    int j = blockIdx.x, t = threadIdx.x;
    unsigned long long m = ~0ull;
    for (int i = t; i < MM / RF_ROWS; i += 256) {
        unsigned long long v = refpart[(size_t)i * 32 + j];
        if (v < m) m = v;
    }
    red[t] = m;
    __syncthreads();
    for (int s = 128; s; s >>= 1) {
        if (t < s && red[t + s] < red[t]) red[t] = red[t + s];
        __syncthreads();
    }
    if (t == 0) keys2[j] = red[0];
}

__global__ void k_final(const unsigned long long* __restrict__ keys2, const int* __restrict__ cand,
                        int* __restrict__ mp, float* __restrict__ scb, int* __restrict__ nn) {
    int b = threadIdx.x;
    if (b < BB) {
        float bestsc = -1.f;
        int bestpatch = 1 << 20, bestnn = 0;
        for (int k = 0; k < 4; k++) {
            unsigned long long key = keys2[b * 4 + k];
            float sc = sqrtf(__uint_as_float((unsigned)(key >> 32)));
            int patch = cand[b * 4 + k] & 255;
            int nnidx = (int)(key & 0xffffffffu);
            if (sc > bestsc || (sc == bestsc && patch < bestpatch)) {
                bestsc = sc; bestpatch = patch; bestnn = nnidx;
            }
        }
        mp[b] = bestpatch; scb[b] = bestsc; nn[b] = bestnn;
    }
}

// ---------------- K12: d_nn ----------------
__global__ void k_dnn(const float* __restrict__ mb, const float* __restrict__ yn,
                      const int* __restrict__ nn, float* __restrict__ dnn) {
    __shared__ float nnf[BB][CC];
    int t = threadIdx.x;
    for (int i = t; i < BB * CC; i += 256) {
        int bb = i / CC, cc = i % CC;
        nnf[bb][cc] = mb[(size_t)nn[bb] * CC + cc];
    }
    __syncthreads();
    int w = t >> 6, l = t & 63;
    int m = blockIdx.x * 4 + w;
    float accv[BB];
#pragma unroll
    for (int b = 0; b < BB; b++) accv[b] = 0.f;
    const float* r = mb + (size_t)m * CC;
#pragma unroll
    for (int i = 0; i < 6; i++) {
        float v = r[i * 64 + l];
#pragma unroll
        for (int b = 0; b < BB; b++) accv[b] = fmaf(v, nnf[b][i * 64 + l], accv[b]);
    }
#pragma unroll
    for (int b = 0; b < BB; b++) {
        float s = accv[b];
#pragma unroll
        for (int mm = 32; mm; mm >>= 1) s += __shfl_xor(s, mm);
        if (l == 0) {
            float d2 = fmaxf(yn[nn[b]] - 2.f * s + yn[m], 0.f);
            dnn[(size_t)b * MM + m] = sqrtf(d2);
        }
    }
}

// ---------------- K13: top-9 ----------------
__global__ void k_top9(const float* __restrict__ dnn, int* __restrict__ sup) {
    __shared__ float sd[256][TOPK];
    __shared__ int sx[256][TOPK];
    int b = blockIdx.x, t = threadIdx.x;
    float ld[TOPK];
    int li[TOPK];
#pragma unroll
    for (int k = 0; k < TOPK; k++) { ld[k] = INFINITY; li[k] = MM; }
    const float* d = dnn + (size_t)b * MM;
    for (int m = t; m < MM; m += 256) {
        float v = d[m];
        if (v < ld[TOPK - 1] || (v == ld[TOPK - 1] && m < li[TOPK - 1])) {
            int k = TOPK - 1;
            while (k > 0 && (v < ld[k - 1] || (v == ld[k - 1] && m < li[k - 1]))) {
                ld[k] = ld[k - 1]; li[k] = li[k - 1]; k--;
            }
            ld[k] = v; li[k] = m;
        }
    }
    for (int k = 0; k < TOPK; k++) { sd[t][k] = ld[k]; sx[t][k] = li[k]; }
    __syncthreads();
    for (int s = 128; s; s >>= 1) {
        if (t < s) {
            float md[TOPK]; int mi[TOPK];
            int p = 0, q = 0;
            for (int k = 0; k < TOPK; k++) {
                float va = sd[t][p], vb = sd[t + s][q];
                int ia = sx[t][p], ib = sx[t + s][q];
                bool ta = (va < vb) || (va == vb && ia < ib);
                if (ta) { md[k] = va; mi[k] = ia; p++; }
                else    { md[k] = vb; mi[k] = ib; q++; }
            }
            for (int k = 0; k < TOPK; k++) { sd[t][k] = md[k]; sx[t][k] = mi[k]; }
        }
        __syncthreads();
    }
    if (t < TOPK) sup[b * TOPK + t] = sx[0][t];
}

// ---------------- K14: pred_score ----------------
__global__ void k_pred(const float* __restrict__ emb, const float* __restrict__ mb,
                       const float* __restrict__ yn, const float* __restrict__ xn,
                       const int* __restrict__ mp, const float* __restrict__ scb,
                       const int* __restrict__ sup, float* __restrict__ outp) {
    __shared__ float ds[TOPK];
    int b = blockIdx.x;
    int t = threadIdx.x;
    int w = t >> 6, l = t & 63;
    int mpb = mp[b];
    const float* mf = emb + ((size_t)b * SS + mpb) * CC;
    float xr = xn[b * SS + mpb];
    for (int k = w; k < TOPK; k += 4) {
        int sidx = sup[b * TOPK + k];
        const float* sr = mb + (size_t)sidx * CC;
        float s = 0.f;
#pragma unroll
        for (int i = 0; i < 6; i++) s = fmaf(mf[i * 64 + l], sr[i * 64 + l], s);
#pragma unroll
        for (int mm = 32; mm; mm >>= 1) s += __shfl_xor(s, mm);
        if (l == 0) ds[k] = sqrtf(fmaxf(xr - 2.f * s + yn[sidx], 0.f));
    }
    __syncthreads();
    if (t == 0) {
        float mx = ds[0];
        for (int k = 1; k < TOPK; k++) mx = fmaxf(mx, ds[k]);
        float num = expf(ds[0] - mx), den = 0.f;
        for (int k = 0; k < TOPK; k++) den += expf(ds[k] - mx);
        outp[b] = (1.f - num / den) * scb[b];
    }
}

// ---------------- K15: anomaly map scatter ----------------
__global__ void k_map(const float* __restrict__ scores, const int* __restrict__ labels,
                      float* __restrict__ out) {
    size_t i = (size_t)blockIdx.x * 256 + threadIdx.x;
    int b = (int)(i / HWP);
    out[i] = scores[b * SS + labels[i]];
}

extern "C" void kernel_launch(void* const* d_in, const int* in_sizes, int n_in,
                              void* d_out, int out_size, void* d_ws, size_t ws_size,
                              hipStream_t stream) {
    const float* feats  = (const float*)d_in[0];
    const int*   labels = (const int*)d_in[1];
    const float* mb     = (const float*)d_in[2];
    float* out = (float*)d_out;

    char* ws = (char*)d_ws;
    const size_t SZ_MBH   = (size_t)MM * CC * 2;
    const size_t SZ_EMBH  = (size_t)GM * CC * 2;
    const size_t SZ_EMB   = (size_t)GM * CC * 4;
    const size_t SZ_YN    = (size_t)MM * 4;
    const size_t SZ_SMALL = 8192;
    const size_t SZ_P2    = (size_t)8 * GM * 8;
    const size_t SZ_BIG   = (size_t)512 * GM * 8;

    size_t need_full = SZ_MBH + SZ_EMBH + SZ_EMB + SZ_YN + 4 * SZ_SMALL + 2048 + SZ_P2 + SZ_BIG + 512;
    bool lowmem = ws_size < need_full;

    size_t o = 0;
    unsigned short* mbh = nullptr;
    if (!lowmem) { mbh = (unsigned short*)(ws + o); o += SZ_MBH; }
    unsigned short* embh = (unsigned short*)(ws + o); o += SZ_EMBH;
    float* emb = (float*)(ws + o);                    o += SZ_EMB;
    float* yn  = (float*)(ws + o);                    o += SZ_YN;
    float* xn  = (float*)(ws + o);                    o += SZ_SMALL;
    float* cnt = (float*)(ws + o);                    o += SZ_SMALL;
    float* scores = (float*)(ws + o);                 o += SZ_SMALL;
    int*   locs   = (int*)(ws + o);                   o += SZ_SMALL;
    int*   cand   = (int*)(ws + o);                   o += 256;
    unsigned long long* keys2 = (unsigned long long*)(ws + o); o += 256;
    int*   mp  = (int*)(ws + o);                      o += 128;
    float* scb = (float*)(ws + o);                    o += 128;
    int*   nn  = (int*)(ws + o);                      o += 128;
    int*   sup = (int*)(ws + o);                      o += 512;
    o = (o + 255) & ~(size_t)255;
    unsigned long long* partial2 = (unsigned long long*)(ws + o); o += SZ_P2;
    char* big = ws + o;
    unsigned long long* partials = (unsigned long long*)big;
    unsigned long long* refpart  = (unsigned long long*)big;   // reused after partials consumed
    float* dnn = (float*)(big + 4194304);

    hipMemsetAsync(emb, 0, SZ_EMB, stream);
    k_counts<<<BB, 256, 0, stream>>>(labels, cnt);
    k_segsum3<<<dim3(16, 24, BB), 256, 0, stream>>>(feats, labels, emb);
    if (!lowmem) k_cvtmb<<<MM / 4, 256, 0, stream>>>(mb, mbh, yn);
    else         k_ynorm<<<MM / 4, 256, 0, stream>>>(mb, yn);
    k_embfin<<<GM, 64, 0, stream>>>(emb, cnt, xn, embh);

    if (!lowmem)
        k_gemm<false><<<8192, 256, 0, stream>>>(embh, mbh, mb, xn, yn, partials);
    else
        k_gemm<true><<<8192, 256, 0, stream>>>(embh, embh, mb, xn, yn, partials);

    k_reduce1<<<dim3(8, 8), 256, 0, stream>>>(partials, partial2);
    k_reduce2<<<8, 256, 0, stream>>>(partial2, scores, locs);
    k_cand<<<BB, 256, 0, stream>>>(scores, cand);
    k_refine<<<MM / RF_ROWS, 256, 0, stream>>>(emb, mb, xn, yn, cand, refpart);
    k_refred<<<32, 256, 0, stream>>>(refpart, keys2);
    k_final<<<1, 64, 0, stream>>>(keys2, cand, mp, scb, nn);
    k_dnn<<<MM / 4, 256, 0, stream>>>(mb, yn, nn, dnn);
    k_top9<<<BB, 256, 0, stream>>>(dnn, sup);
    k_pred<<<BB, 256, 0, stream>>>(emb, mb, yn, xn, mp, scb, sup, out + (size_t)BB * HWP);
    k_map<<<(BB * HWP) / 256, 256, 0, stream>>>(scores, labels, out);
}

// Round 4
// 1685.399 us; speedup vs baseline: 1.6421x; 1.0021x over previous
//
#include <hip/hip_runtime.h>

#define BB 8
#define CC 384
#define HWP 50176
#define SS 256
#define MM 65536
#define TOPK 9
#define GM 2048          // BB*SS emb rows

typedef __attribute__((ext_vector_type(8))) __bf16 bf16x8;
typedef __attribute__((ext_vector_type(16))) float fx16;

__device__ __forceinline__ unsigned short f2bf_rne(float x) {
    unsigned u = __float_as_uint(x);
    unsigned r = (u + 0x7FFFu + ((u >> 16) & 1u)) >> 16;
    return (unsigned short)r;
}

__device__ __forceinline__ void gl_lds16(const void* g, void* l) {
    auto gp = (const __attribute__((address_space(1))) unsigned int*)g;
    auto lp = (__attribute__((address_space(3))) unsigned int*)l;
    __builtin_amdgcn_global_load_lds(gp, lp, 16, 0, 0);
}

// ---------------- K1: per-batch label counts ----------------
__global__ void k_counts(const int* __restrict__ labels, float* __restrict__ counts) {
    __shared__ unsigned int cnt[SS];
    int b = blockIdx.x, t = threadIdx.x;
    cnt[t] = 0u;
    __syncthreads();
    const int* lb = labels + (size_t)b * HWP;
    for (int p = t; p < HWP; p += 256) atomicAdd(&cnt[lb[p]], 1u);
    __syncthreads();
    counts[b * SS + t] = (float)cnt[t];
}

// ---------------- K2: segment sums v4 ----------------
// Bottleneck was same-address LDS atomic RMW serialization (spatially coherent
// labels -> all 64 lanes hit one address). Fix: (1) merge the 4 components when
// their labels match (~95% of groups, 4x fewer atomics); (2) 2 bank-shifted
// accumulator replicas, half-wave each -> two 32-long chains in parallel banks.
#define PX 3136
__global__ __launch_bounds__(256) void k_segsum4(const float* __restrict__ feats,
                                                 const int* __restrict__ labels,
                                                 float* __restrict__ emb) {
    __shared__ float acc[2][16][257];   // 32.9 KB; replica bank shift 16, channel bank shift 1
    int chunk = blockIdx.x, cg = blockIdx.y, b = blockIdx.z;
    int t = threadIdx.x;
    int rep = (t >> 5) & 1;             // lanes 0-31 -> replica 0, 32-63 -> replica 1
    for (int i = t; i < 2 * 16 * 257; i += 256) ((float*)acc)[i] = 0.f;
    __syncthreads();

    const int4* l4 = (const int4*)(labels + (size_t)b * HWP + (size_t)chunk * PX);
    const float4* f4 = (const float4*)(feats + ((size_t)(b * CC + cg * 16)) * HWP + (size_t)chunk * PX);
    const int CS4 = HWP / 4;

#pragma unroll
    for (int j = 0; j < 4; j++) {
        int p4 = j * 256 + t;
        if (p4 < PX / 4) {
            int4 li = l4[p4];
            float4 vv[16];
#pragma unroll
            for (int c = 0; c < 16; c++) vv[c] = f4[(size_t)c * CS4 + p4];
            __builtin_amdgcn_sched_barrier(0);   // keep all 16 loads issued before atomics
            bool uni = (li.x == li.y) && (li.x == li.z) && (li.x == li.w);
#pragma unroll
            for (int c = 0; c < 16; c++) {
                float4 v = vv[c];
                if (uni) {
                    atomicAdd(&acc[rep][c][li.x], (v.x + v.y) + (v.z + v.w));
                } else {
                    atomicAdd(&acc[rep][c][li.x], v.x);
                    atomicAdd(&acc[rep][c][li.y], v.y);
                    atomicAdd(&acc[rep][c][li.z], v.z);
                    atomicAdd(&acc[rep][c][li.w], v.w);
                }
            }
        }
    }
    __syncthreads();
    for (int i = t; i < 16 * SS; i += 256) {
        int c = i & 15, s = i >> 4;
        float sum = acc[0][c][s] + acc[1][c][s];
        atomicAdd(&emb[(size_t)(b * SS + s) * CC + cg * 16 + c], sum);
    }
}

// ---------------- K3: bank fp32->bf16 + row norms ----------------
__global__ void k_cvtmb(const float* __restrict__ mb, unsigned short* __restrict__ mbh,
                        float* __restrict__ yn) {
    int w = threadIdx.x >> 6, l = threadIdx.x & 63;
    int row = blockIdx.x * 4 + w;
    const float* r = mb + (size_t)row * CC;
    unsigned short* o = mbh + (size_t)row * CC;
    float s = 0.f;
#pragma unroll
    for (int i = 0; i < 6; i++) {
        float v = r[i * 64 + l];
        s = fmaf(v, v, s);
        o[i * 64 + l] = f2bf_rne(v);
    }
#pragma unroll
    for (int m = 32; m; m >>= 1) s += __shfl_xor(s, m);
    if (l == 0) yn[row] = s;
}

__global__ void k_ynorm(const float* __restrict__ mb, float* __restrict__ yn) {
    int w = threadIdx.x >> 6, l = threadIdx.x & 63;
    int row = blockIdx.x * 4 + w;
    const float* r = mb + (size_t)row * CC;
    float s = 0.f;
#pragma unroll
    for (int i = 0; i < 6; i++) { float v = r[i * 64 + l]; s = fmaf(v, v, s); }
#pragma unroll
    for (int m = 32; m; m >>= 1) s += __shfl_xor(s, m);
    if (l == 0) yn[row] = s;
}

// ---------------- K4: finalize emb + norms + bf16 copy ----------------
__global__ void k_embfin(float* __restrict__ emb, const float* __restrict__ counts,
                         float* __restrict__ xn, unsigned short* __restrict__ embh) {
    int i = blockIdx.x, l = threadIdx.x;
    float inv = 1.f / fmaxf(counts[i], 1.f);
    float* e = emb + (size_t)i * CC;
    unsigned short* o = embh + (size_t)i * CC;
    float s = 0.f;
#pragma unroll
    for (int j = 0; j < 6; j++) {
        float v = e[j * 64 + l] * inv;
        e[j * 64 + l] = v;
        o[j * 64 + l] = f2bf_rne(v);
        s = fmaf(v, v, s);
    }
#pragma unroll
    for (int m = 32; m; m >>= 1) s += __shfl_xor(s, m);
    if (l == 0) xn[i] = s;
}

// ---------------- K5: bf16 MFMA GEMM + fused row-min ----------------
template <bool REGB>
__global__ __launch_bounds__(256) void k_gemm(
        const unsigned short* __restrict__ Ah, const unsigned short* __restrict__ Bh,
        const float* __restrict__ Bf,
        const float* __restrict__ xn, const float* __restrict__ yn,
        unsigned long long* __restrict__ partials) {
    __shared__ bf16x8 As[8][128];
    __shared__ bf16x8 Bs[8][128];
    __shared__ unsigned long long rowbest[128];
    int bid = blockIdx.x;
    int swz = (bid & 7) * 1024 + (bid >> 3);
    int rb = swz & 15, nb = swz >> 4;
    int t = threadIdx.x;
    int w = t >> 6, l = t & 63;
    int wm = w & 1, wn = w >> 1;

    if (t < 128) rowbest[t] = ~0ull;

    fx16 acc00, acc01, acc10, acc11;
#pragma unroll
    for (int p = 0; p < 16; p++) { acc00[p] = 0.f; acc01[p] = 0.f; acc10[p] = 0.f; acc11[p] = 0.f; }

    const unsigned short* Abase = Ah + (size_t)(rb * 128) * CC;
    const unsigned short* Bbase = REGB ? nullptr : (Bh + (size_t)(nb * 128) * CC);
    const float* Bfbase = Bf + (size_t)(nb * 128) * CC;

    for (int kt = 0; kt < 6; kt++) {
        int k0 = kt * 64;
#pragma unroll
        for (int q = 0; q < 4; q++) {
            int c = q * 256 + t;
            int r = c & 127, g = c >> 7;
            gl_lds16(Abase + (size_t)r * CC + k0 + g * 8, &As[g][r]);
            if (!REGB) {
                gl_lds16(Bbase + (size_t)r * CC + k0 + g * 8, &Bs[g][r]);
            } else {
                const float* src = Bfbase + (size_t)r * CC + k0 + g * 8;
                float4 v0 = *(const float4*)(src);
                float4 v1 = *(const float4*)(src + 4);
                unsigned short tmp[8];
                tmp[0] = f2bf_rne(v0.x); tmp[1] = f2bf_rne(v0.y);
                tmp[2] = f2bf_rne(v0.z); tmp[3] = f2bf_rne(v0.w);
                tmp[4] = f2bf_rne(v1.x); tmp[5] = f2bf_rne(v1.y);
                tmp[6] = f2bf_rne(v1.z); tmp[7] = f2bf_rne(v1.w);
                Bs[g][r] = *(const bf16x8*)tmp;
            }
        }
        __syncthreads();
#pragma unroll
        for (int s = 0; s < 4; s++) {
            int g = s * 2 + (l >> 5);
            bf16x8 a0 = As[g][wm * 64 + (l & 31)];
            bf16x8 a1 = As[g][wm * 64 + 32 + (l & 31)];
            bf16x8 b0 = Bs[g][wn * 64 + (l & 31)];
            bf16x8 b1 = Bs[g][wn * 64 + 32 + (l & 31)];
            acc00 = __builtin_amdgcn_mfma_f32_32x32x16_bf16(a0, b0, acc00, 0, 0, 0);
            acc01 = __builtin_amdgcn_mfma_f32_32x32x16_bf16(a0, b1, acc01, 0, 0, 0);
            acc10 = __builtin_amdgcn_mfma_f32_32x32x16_bf16(a1, b0, acc10, 0, 0, 0);
            acc11 = __builtin_amdgcn_mfma_f32_32x32x16_bf16(a1, b1, acc11, 0, 0, 0);
        }
        __syncthreads();
    }

    int colg0 = nb * 128 + wn * 64 + (l & 31);
    int colg1 = colg0 + 32;
    float yn0 = yn[colg0], yn1 = yn[colg1];
#pragma unroll
    for (int i = 0; i < 2; i++) {
#pragma unroll
        for (int p = 0; p < 16; p++) {
            float a0v = (i == 0) ? acc00[p] : acc10[p];
            float a1v = (i == 0) ? acc01[p] : acc11[p];
            int rl = i * 32 + (p & 3) + 8 * (p >> 2) + 4 * (l >> 5);
            int grow = rb * 128 + wm * 64 + rl;
            float xr = xn[grow];
            float d0 = fmaxf(xr - 2.f * a0v + yn0, 0.f);
            float d1 = fmaxf(xr - 2.f * a1v + yn1, 0.f);
            unsigned long long k0 = ((unsigned long long)__float_as_uint(d0) << 32) | (unsigned)colg0;
            unsigned long long k1 = ((unsigned long long)__float_as_uint(d1) << 32) | (unsigned)colg1;
            unsigned long long best = k0 < k1 ? k0 : k1;
#pragma unroll
            for (int m = 1; m < 32; m <<= 1) {
                unsigned long long o2 = __shfl_xor(best, m);
                if (o2 < best) best = o2;
            }
            if ((l & 31) == 0) atomicMin(&rowbest[wm * 64 + rl], best);
        }
    }
    __syncthreads();
    if (t < 128) partials[(size_t)nb * GM + rb * 128 + t] = rowbest[t];
}

// ---------------- K6/K7: two-stage min reduction ----------------
__global__ void k_reduce1(const unsigned long long* __restrict__ partials,
                          unsigned long long* __restrict__ partial2) {
    int row = blockIdx.x * 256 + threadIdx.x;
    int ng = blockIdx.y;
    unsigned long long m = ~0ull;
    for (int n = 0; n < 64; n++) {
        unsigned long long v = partials[(size_t)(ng * 64 + n) * GM + row];
        if (v < m) m = v;
    }
    partial2[ng * GM + row] = m;
}

__global__ void k_reduce2(const unsigned long long* __restrict__ partial2,
                          float* __restrict__ scores, int* __restrict__ locs) {
    int row = blockIdx.x * 256 + threadIdx.x;
    unsigned long long m = ~0ull;
    for (int g = 0; g < 8; g++) {
        unsigned long long v = partial2[g * GM + row];
        if (v < m) m = v;
    }
    scores[row] = sqrtf(__uint_as_float((unsigned)(m >> 32)));
    locs[row] = (int)(m & 0xffffffffu);
}

// ---------------- K8: per-batch top-4 candidates ----------------
__global__ void k_cand(const float* __restrict__ scores, int* __restrict__ cand) {
    __shared__ unsigned long long key[256];
    __shared__ unsigned long long red[256];
    int b = blockIdx.x, t = threadIdx.x;
    float sc = scores[b * SS + t];
    key[t] = ((unsigned long long)__float_as_uint(sc) << 32) | (unsigned)(255 - t);
    __syncthreads();
    for (int k = 0; k < 4; k++) {
        red[t] = key[t];
        __syncthreads();
        for (int s = 128; s; s >>= 1) {
            if (t < s && red[t + s] > red[t]) red[t] = red[t + s];
            __syncthreads();
        }
        unsigned long long win = red[0];
        int patch = 255 - (int)(win & 0xffffffffu);
        if (t == 0) cand[b * 4 + k] = b * SS + patch;
        __syncthreads();
        if (t == patch) key[t] = 0;
        __syncthreads();
    }
}

// ---------------- K9: exact fp32 re-search for 32 candidate rows ----------------
#define RF_ROWS 8
__global__ __launch_bounds__(256) void k_refine(
        const float* __restrict__ emb, const float* __restrict__ mb,
        const float* __restrict__ xn, const float* __restrict__ yn,
        const int* __restrict__ cand, unsigned long long* __restrict__ refpart) {
    __shared__ float cl[32 * CC];
    __shared__ float xnc[32];
    __shared__ int cr[32];
    __shared__ unsigned long long bmin[32];
    int t = threadIdx.x;
    if (t < 32) cr[t] = cand[t];
    __syncthreads();
    if (t < 32) { xnc[t] = xn[cr[t]]; bmin[t] = ~0ull; }
    for (int i = t; i < 32 * CC; i += 256) {
        int j = i / CC, p = i - j * CC;
        cl[i] = emb[(size_t)cr[j] * CC + p];
    }
    __syncthreads();
    int w = t >> 6, l = t & 63;
    int m0 = blockIdx.x * RF_ROWS + w * 2, m1 = m0 + 1;
    float2 r0[3], r1[3];
#pragma unroll
    for (int c = 0; c < 3; c++) {
        r0[c] = *(const float2*)&mb[(size_t)m0 * CC + c * 128 + l * 2];
        r1[c] = *(const float2*)&mb[(size_t)m1 * CC + c * 128 + l * 2];
    }
    float ya = yn[m0], yb = yn[m1];
    for (int j = 0; j < 32; j++) {
        float s0 = 0.f, s1 = 0.f;
#pragma unroll
        for (int c = 0; c < 3; c++) {
            float2 cv = *(const float2*)&cl[j * CC + c * 128 + l * 2];
            s0 = fmaf(r0[c].x, cv.x, s0); s0 = fmaf(r0[c].y, cv.y, s0);
            s1 = fmaf(r1[c].x, cv.x, s1); s1 = fmaf(r1[c].y, cv.y, s1);
        }
#pragma unroll
        for (int mm = 32; mm; mm >>= 1) { s0 += __shfl_xor(s0, mm); s1 += __shfl_xor(s1, mm); }
        if (l == 0) {
            float d0 = fmaxf(xnc[j] - 2.f * s0 + ya, 0.f);
            float d1 = fmaxf(xnc[j] - 2.f * s1 + yb, 0.f);
            unsigned long long k0 = ((unsigned long long)__float_as_uint(d0) << 32) | (unsigned)m0;
            unsigned long long k1 = ((unsigned long long)__float_as_uint(d1) << 32) | (unsigned)m1;
            unsigned long long kb = k0 < k1 ? k0 : k1;
            atomicMin(&bmin[j], kb);
        }
    }
    __syncthreads();
    if (t < 32) refpart[(size_t)blockIdx.x * 32 + t] = bmin[t];
}

__global__ void k_refred(const unsigned long long* __restrict__ refpart,
                         unsigned long long* __restrict__ keys2) {
    __shared__ unsigned long long red[256];
    int j = blockIdx.x, t = threadIdx.x;
    unsigned long long m = ~0ull;
    for (int i = t; i < MM / RF_ROWS; i += 256) {
        unsigned long long v = refpart[(size_t)i * 32 + j];
        if (v < m) m = v;
    }
    red[t] = m;
    __syncthreads();
    for (int s = 128; s; s >>= 1) {
        if (t < s && red[t + s] < red[t]) red[t] = red[t + s];
        __syncthreads();
    }
    if (t == 0) keys2[j] = red[0];
}

__global__ void k_final(const unsigned long long* __restrict__ keys2, const int* __restrict__ cand,
                        int* __restrict__ mp, float* __restrict__ scb, int* __restrict__ nn) {
    int b = threadIdx.x;
    if (b < BB) {
        float bestsc = -1.f;
        int bestpatch = 1 << 20, bestnn = 0;
        for (int k = 0; k < 4; k++) {
            unsigned long long key = keys2[b * 4 + k];
            float sc = sqrtf(__uint_as_float((unsigned)(key >> 32)));
            int patch = cand[b * 4 + k] & 255;
            int nnidx = (int)(key & 0xffffffffu);
            if (sc > bestsc || (sc == bestsc && patch < bestpatch)) {
                bestsc = sc; bestpatch = patch; bestnn = nnidx;
            }
        }
        mp[b] = bestpatch; scb[b] = bestsc; nn[b] = bestnn;
    }
}

// ---------------- K12: d_nn ----------------
__global__ void k_dnn(const float* __restrict__ mb, const float* __restrict__ yn,
                      const int* __restrict__ nn, float* __restrict__ dnn) {
    __shared__ float nnf[BB][CC];
    int t = threadIdx.x;
    for (int i = t; i < BB * CC; i += 256) {
        int bb = i / CC, cc = i % CC;
        nnf[bb][cc] = mb[(size_t)nn[bb] * CC + cc];
    }
    __syncthreads();
    int w = t >> 6, l = t & 63;
    int m = blockIdx.x * 4 + w;
    float accv[BB];
#pragma unroll
    for (int b = 0; b < BB; b++) accv[b] = 0.f;
    const float* r = mb + (size_t)m * CC;
#pragma unroll
    for (int i = 0; i < 6; i++) {
        float v = r[i * 64 + l];
#pragma unroll
        for (int b = 0; b < BB; b++) accv[b] = fmaf(v, nnf[b][i * 64 + l], accv[b]);
    }
#pragma unroll
    for (int b = 0; b < BB; b++) {
        float s = accv[b];
#pragma unroll
        for (int mm = 32; mm; mm >>= 1) s += __shfl_xor(s, mm);
        if (l == 0) {
            float d2 = fmaxf(yn[nn[b]] - 2.f * s + yn[m], 0.f);
            dnn[(size_t)b * MM + m] = sqrtf(d2);
        }
    }
}

// ---------------- K13: top-9 ----------------
__global__ void k_top9(const float* __restrict__ dnn, int* __restrict__ sup) {
    __shared__ float sd[256][TOPK];
    __shared__ int sx[256][TOPK];
    int b = blockIdx.x, t = threadIdx.x;
    float ld[TOPK];
    int li[TOPK];
#pragma unroll
    for (int k = 0; k < TOPK; k++) { ld[k] = INFINITY; li[k] = MM; }
    const float* d = dnn + (size_t)b * MM;
    for (int m = t; m < MM; m += 256) {
        float v = d[m];
        if (v < ld[TOPK - 1] || (v == ld[TOPK - 1] && m < li[TOPK - 1])) {
            int k = TOPK - 1;
            while (k > 0 && (v < ld[k - 1] || (v == ld[k - 1] && m < li[k - 1]))) {
                ld[k] = ld[k - 1]; li[k] = li[k - 1]; k--;
            }
            ld[k] = v; li[k] = m;
        }
    }
    for (int k = 0; k < TOPK; k++) { sd[t][k] = ld[k]; sx[t][k] = li[k]; }
    __syncthreads();
    for (int s = 128; s; s >>= 1) {
        if (t < s) {
            float md[TOPK]; int mi[TOPK];
            int p = 0, q = 0;
            for (int k = 0; k < TOPK; k++) {
                float va = sd[t][p], vb = sd[t + s][q];
                int ia = sx[t][p], ib = sx[t + s][q];
                bool ta = (va < vb) || (va == vb && ia < ib);
                if (ta) { md[k] = va; mi[k] = ia; p++; }
                else    { md[k] = vb; mi[k] = ib; q++; }
            }
            for (int k = 0; k < TOPK; k++) { sd[t][k] = md[k]; sx[t][k] = mi[k]; }
        }
        __syncthreads();
    }
    if (t < TOPK) sup[b * TOPK + t] = sx[0][t];
}

// ---------------- K14: pred_score ----------------
__global__ void k_pred(const float* __restrict__ emb, const float* __restrict__ mb,
                       const float* __restrict__ yn, const float* __restrict__ xn,
                       const int* __restrict__ mp, const float* __restrict__ scb,
                       const int* __restrict__ sup, float* __restrict__ outp) {
    __shared__ float ds[TOPK];
    int b = blockIdx.x;
    int t = threadIdx.x;
    int w = t >> 6, l = t & 63;
    int mpb = mp[b];
    const float* mf = emb + ((size_t)b * SS + mpb) * CC;
    float xr = xn[b * SS + mpb];
    for (int k = w; k < TOPK; k += 4) {
        int sidx = sup[b * TOPK + k];
        const float* sr = mb + (size_t)sidx * CC;
        float s = 0.f;
#pragma unroll
        for (int i = 0; i < 6; i++) s = fmaf(mf[i * 64 + l], sr[i * 64 + l], s);
#pragma unroll
        for (int mm = 32; mm; mm >>= 1) s += __shfl_xor(s, mm);
        if (l == 0) ds[k] = sqrtf(fmaxf(xr - 2.f * s + yn[sidx], 0.f));
    }
    __syncthreads();
    if (t == 0) {
        float mx = ds[0];
        for (int k = 1; k < TOPK; k++) mx = fmaxf(mx, ds[k]);
        float num = expf(ds[0] - mx), den = 0.f;
        for (int k = 0; k < TOPK; k++) den += expf(ds[k] - mx);
        outp[b] = (1.f - num / den) * scb[b];
    }
}

// ---------------- K15: anomaly map scatter ----------------
__global__ void k_map(const float* __restrict__ scores, const int* __restrict__ labels,
                      float* __restrict__ out) {
    size_t i = (size_t)blockIdx.x * 256 + threadIdx.x;
    int b = (int)(i / HWP);
    out[i] = scores[b * SS + labels[i]];
}

extern "C" void kernel_launch(void* const* d_in, const int* in_sizes, int n_in,
                              void* d_out, int out_size, void* d_ws, size_t ws_size,
                              hipStream_t stream) {
    const float* feats  = (const float*)d_in[0];
    const int*   labels = (const int*)d_in[1];
    const float* mb     = (const float*)d_in[2];
    float* out = (float*)d_out;

    char* ws = (char*)d_ws;
    const size_t SZ_MBH   = (size_t)MM * CC * 2;
    const size_t SZ_EMBH  = (size_t)GM * CC * 2;
    const size_t SZ_EMB   = (size_t)GM * CC * 4;
    const size_t SZ_YN    = (size_t)MM * 4;
    const size_t SZ_SMALL = 8192;
    const size_t SZ_P2    = (size_t)8 * GM * 8;
    const size_t SZ_BIG   = (size_t)512 * GM * 8;

    size_t need_full = SZ_MBH + SZ_EMBH + SZ_EMB + SZ_YN + 4 * SZ_SMALL + 2048 + SZ_P2 + SZ_BIG + 512;
    bool lowmem = ws_size < need_full;

    size_t o = 0;
    unsigned short* mbh = nullptr;
    if (!lowmem) { mbh = (unsigned short*)(ws + o); o += SZ_MBH; }
    unsigned short* embh = (unsigned short*)(ws + o); o += SZ_EMBH;
    float* emb = (float*)(ws + o);                    o += SZ_EMB;
    float* yn  = (float*)(ws + o);                    o += SZ_YN;
    float* xn  = (float*)(ws + o);                    o += SZ_SMALL;
    float* cnt = (float*)(ws + o);                    o += SZ_SMALL;
    float* scores = (float*)(ws + o);                 o += SZ_SMALL;
    int*   locs   = (int*)(ws + o);                   o += SZ_SMALL;
    int*   cand   = (int*)(ws + o);                   o += 256;
    unsigned long long* keys2 = (unsigned long long*)(ws + o); o += 256;
    int*   mp  = (int*)(ws + o);                      o += 128;
    float* scb = (float*)(ws + o);                    o += 128;
    int*   nn  = (int*)(ws + o);                      o += 128;
    int*   sup = (int*)(ws + o);                      o += 512;
    o = (o + 255) & ~(size_t)255;
    unsigned long long* partial2 = (unsigned long long*)(ws + o); o += SZ_P2;
    char* big = ws + o;
    unsigned long long* partials = (unsigned long long*)big;
    unsigned long long* refpart  = (unsigned long long*)big;   // reused after partials consumed
    float* dnn = (float*)(big + 4194304);

    hipMemsetAsync(emb, 0, SZ_EMB, stream);
    k_counts<<<BB, 256, 0, stream>>>(labels, cnt);
    k_segsum4<<<dim3(16, 24, BB), 256, 0, stream>>>(feats, labels, emb);
    if (!lowmem) k_cvtmb<<<MM / 4, 256, 0, stream>>>(mb, mbh, yn);
    else         k_ynorm<<<MM / 4, 256, 0, stream>>>(mb, yn);
    k_embfin<<<GM, 64, 0, stream>>>(emb, cnt, xn, embh);

    if (!lowmem)
        k_gemm<false><<<8192, 256, 0, stream>>>(embh, mbh, mb, xn, yn, partials);
    else
        k_gemm<true><<<8192, 256, 0, stream>>>(embh, embh, mb, xn, yn, partials);

    k_reduce1<<<dim3(8, 8), 256, 0, stream>>>(partials, partial2);
    k_reduce2<<<8, 256, 0, stream>>>(partial2, scores, locs);
    k_cand<<<BB, 256, 0, stream>>>(scores, cand);
    k_refine<<<MM / RF_ROWS, 256, 0, stream>>>(emb, mb, xn, yn, cand, refpart);
    k_refred<<<32, 256, 0, stream>>>(refpart, keys2);
    k_final<<<1, 64, 0, stream>>>(keys2, cand, mp, scb, nn);
    k_dnn<<<MM / 4, 256, 0, stream>>>(mb, yn, nn, dnn);
    k_top9<<<BB, 256, 0, stream>>>(dnn, sup);
    k_pred<<<BB, 256, 0, stream>>>(emb, mb, yn, xn, mp, scb, sup, out + (size_t)BB * HWP);
    k_map<<<(BB * HWP) / 256, 256, 0, stream>>>(scores, labels, out);
}

// Round 5
// 1133.675 us; speedup vs baseline: 2.4412x; 1.4867x over previous
//
#include <hip/hip_runtime.h>

#define BB 8
#define CC 384
#define HWP 50176
#define SS 256
#define MM 65536
#define TOPK 9
#define GM 2048          // BB*SS emb rows

typedef __attribute__((ext_vector_type(8))) __bf16 bf16x8;
typedef __attribute__((ext_vector_type(16))) float fx16;
typedef __attribute__((ext_vector_type(4))) float f32x4;

__device__ __forceinline__ unsigned short f2bf_rne(float x) {
    unsigned u = __float_as_uint(x);
    unsigned r = (u + 0x7FFFu + ((u >> 16) & 1u)) >> 16;
    return (unsigned short)r;
}

__device__ __forceinline__ void gl_lds16(const void* g, void* l) {
    auto gp = (const __attribute__((address_space(1))) unsigned int*)g;
    auto lp = (__attribute__((address_space(3))) unsigned int*)l;
    __builtin_amdgcn_global_load_lds(gp, lp, 16, 0, 0);
}

// ---------------- K1: per-batch label counts (parallel) ----------------
__global__ void k_counts2(const int* __restrict__ labels, unsigned* __restrict__ cntU) {
    __shared__ unsigned cnt[SS];
    int kc = blockIdx.x, b = blockIdx.y;   // (49, 8)
    int t = threadIdx.x;
    cnt[t] = 0u;
    __syncthreads();
    int4 lv = ((const int4*)(labels + (size_t)b * HWP + kc * 1024))[t];
    atomicAdd(&cnt[lv.x], 1u);
    atomicAdd(&cnt[lv.y], 1u);
    atomicAdd(&cnt[lv.z], 1u);
    atomicAdd(&cnt[lv.w], 1u);
    __syncthreads();
    if (cnt[t]) atomicAdd(&cntU[b * SS + t], cnt[t]);
}

// ---------------- K2: segment sums as one-hot MFMA GEMM ----------------
// emb[s,c] = sum_p onehot[s,p] * feats[c,p].  M=256, N=384, K=50176 per batch.
// A one-hot generated in registers from labels (exact); B = feats bf16 staged in LDS.
// grid (kc=16, cg=6, b=8); block 256 = 4 waves, wave w owns c-cols [cg*64+w*16, +16).
__global__ __launch_bounds__(256) void k_segsum5(const float* __restrict__ feats,
                                                 const int* __restrict__ labels,
                                                 float* __restrict__ emb) {
    __shared__ bf16x8 Bs[8][64];    // Bs[g][c_local] = feats[c][k0+g*8 .. +7], 8 KB
    __shared__ int labL[64];
    __shared__ unsigned smaskL[2];
    int kc = blockIdx.x, cg = blockIdx.y, b = blockIdx.z;
    int t = threadIdx.x, l = t & 63, w = t >> 6;
    int c0b = cg * 64;
    int c0w = c0b + w * 16;
    int g16 = l >> 4;        // 16-lane group 0..3
    int rowl = l & 15;

    f32x4 acc[16];
#pragma unroll
    for (int j = 0; j < 16; j++) acc[j] = (f32x4){0.f, 0.f, 0.f, 0.f};
    unsigned bmask = 0;
    if (t == 0) { smaskL[0] = 0u; smaskL[1] = 0u; }  // same wave as t<16 ORs -> in-order

    const float* fb = feats + ((size_t)b * CC + c0b) * HWP;

    for (int tt = 0; tt < 49; tt++) {
        int k0 = kc * 3136 + tt * 64;
        // --- stage labels (+ active-j mask) and feats tile ---
        if (t < 16) {
            int4 lv = ((const int4*)(labels + (size_t)b * HWP + k0))[t];
            ((int4*)labL)[t] = lv;
            unsigned m = (1u << (lv.x >> 4)) | (1u << (lv.y >> 4)) |
                         (1u << (lv.z >> 4)) | (1u << (lv.w >> 4));
            atomicOr(&smaskL[tt & 1], m);
        }
#pragma unroll
        for (int q = 0; q < 2; q++) {
            int id = t * 2 + q;
            int cl = id >> 3, g = id & 7;
            const float* src = fb + (size_t)cl * HWP + k0 + g * 8;
            float4 v0 = *(const float4*)src;
            float4 v1 = *(const float4*)(src + 4);
            union { unsigned u[4]; bf16x8 v; } pk;
            pk.u[0] = ((unsigned)f2bf_rne(v0.y) << 16) | f2bf_rne(v0.x);
            pk.u[1] = ((unsigned)f2bf_rne(v0.w) << 16) | f2bf_rne(v0.z);
            pk.u[2] = ((unsigned)f2bf_rne(v1.y) << 16) | f2bf_rne(v1.x);
            pk.u[3] = ((unsigned)f2bf_rne(v1.w) << 16) | f2bf_rne(v1.z);
            Bs[g][cl] = pk.v;
        }
        __syncthreads();
        // --- compute ---
        unsigned sm = __builtin_amdgcn_readfirstlane(smaskL[tt & 1]);
        bmask |= sm;
        if (t == 0) smaskL[(tt + 1) & 1] = 0u;   // pre-zero next slot (other slot, safe)
        bf16x8 bf0 = Bs[0 * 4 + g16][w * 16 + rowl];
        bf16x8 bf1 = Bs[1 * 4 + g16][w * 16 + rowl];
        int4 la0 = ((int4*)labL)[g16 * 2 + 0];       // ks=0: k = g16*8 + e
        int4 la1 = ((int4*)labL)[g16 * 2 + 1];
        int4 lb0 = ((int4*)labL)[8 + g16 * 2 + 0];   // ks=1: k = 32 + g16*8 + e
        int4 lb1 = ((int4*)labL)[8 + g16 * 2 + 1];
#pragma unroll
        for (int j = 0; j < 16; j++) {
            if (sm & (1u << j)) {
                int tgt = j * 16 + rowl;
                union { unsigned u[4]; bf16x8 v; } A;
                A.u[0] = (la0.x == tgt ? 0x3F80u : 0u) | (la0.y == tgt ? 0x3F800000u : 0u);
                A.u[1] = (la0.z == tgt ? 0x3F80u : 0u) | (la0.w == tgt ? 0x3F800000u : 0u);
                A.u[2] = (la1.x == tgt ? 0x3F80u : 0u) | (la1.y == tgt ? 0x3F800000u : 0u);
                A.u[3] = (la1.z == tgt ? 0x3F80u : 0u) | (la1.w == tgt ? 0x3F800000u : 0u);
                acc[j] = __builtin_amdgcn_mfma_f32_16x16x32_bf16(A.v, bf0, acc[j], 0, 0, 0);
                A.u[0] = (lb0.x == tgt ? 0x3F80u : 0u) | (lb0.y == tgt ? 0x3F800000u : 0u);
                A.u[1] = (lb0.z == tgt ? 0x3F80u : 0u) | (lb0.w == tgt ? 0x3F800000u : 0u);
                A.u[2] = (lb1.x == tgt ? 0x3F80u : 0u) | (lb1.y == tgt ? 0x3F800000u : 0u);
                A.u[3] = (lb1.z == tgt ? 0x3F80u : 0u) | (lb1.w == tgt ? 0x3F800000u : 0u);
                acc[j] = __builtin_amdgcn_mfma_f32_16x16x32_bf16(A.v, bf1, acc[j], 0, 0, 0);
            }
        }
        __syncthreads();
    }
    // --- flush: C row = j*16 + g16*4 + r, col = c0w + rowl ---
#pragma unroll
    for (int j = 0; j < 16; j++) {
        if (bmask & (1u << j)) {
#pragma unroll
            for (int r = 0; r < 4; r++) {
                float v = acc[j][r];
                int s = j * 16 + g16 * 4 + r;
                if (v != 0.f)
                    atomicAdd(&emb[((size_t)b * SS + s) * CC + c0w + rowl], v);
            }
        }
    }
}

// ---------------- K3: bank fp32->bf16 + row norms ----------------
__global__ void k_cvtmb(const float* __restrict__ mb, unsigned short* __restrict__ mbh,
                        float* __restrict__ yn) {
    int w = threadIdx.x >> 6, l = threadIdx.x & 63;
    int row = blockIdx.x * 4 + w;
    const float* r = mb + (size_t)row * CC;
    unsigned short* o = mbh + (size_t)row * CC;
    float s = 0.f;
#pragma unroll
    for (int i = 0; i < 6; i++) {
        float v = r[i * 64 + l];
        s = fmaf(v, v, s);
        o[i * 64 + l] = f2bf_rne(v);
    }
#pragma unroll
    for (int m = 32; m; m >>= 1) s += __shfl_xor(s, m);
    if (l == 0) yn[row] = s;
}

__global__ void k_ynorm(const float* __restrict__ mb, float* __restrict__ yn) {
    int w = threadIdx.x >> 6, l = threadIdx.x & 63;
    int row = blockIdx.x * 4 + w;
    const float* r = mb + (size_t)row * CC;
    float s = 0.f;
#pragma unroll
    for (int i = 0; i < 6; i++) { float v = r[i * 64 + l]; s = fmaf(v, v, s); }
#pragma unroll
    for (int m = 32; m; m >>= 1) s += __shfl_xor(s, m);
    if (l == 0) yn[row] = s;
}

// ---------------- K4: finalize emb + norms + bf16 copy ----------------
__global__ void k_embfin(float* __restrict__ emb, const unsigned* __restrict__ counts,
                         float* __restrict__ xn, unsigned short* __restrict__ embh) {
    int i = blockIdx.x, l = threadIdx.x;
    float inv = 1.f / fmaxf((float)counts[i], 1.f);
    float* e = emb + (size_t)i * CC;
    unsigned short* o = embh + (size_t)i * CC;
    float s = 0.f;
#pragma unroll
    for (int j = 0; j < 6; j++) {
        float v = e[j * 64 + l] * inv;
        e[j * 64 + l] = v;
        o[j * 64 + l] = f2bf_rne(v);
        s = fmaf(v, v, s);
    }
#pragma unroll
    for (int m = 32; m; m >>= 1) s += __shfl_xor(s, m);
    if (l == 0) xn[i] = s;
}

// ---------------- K5: bf16 MFMA GEMM + fused row-min ----------------
template <bool REGB>
__global__ __launch_bounds__(256) void k_gemm(
        const unsigned short* __restrict__ Ah, const unsigned short* __restrict__ Bh,
        const float* __restrict__ Bf,
        const float* __restrict__ xn, const float* __restrict__ yn,
        unsigned long long* __restrict__ partials) {
    __shared__ bf16x8 As[8][128];
    __shared__ bf16x8 Bs[8][128];
    __shared__ unsigned long long rowbest[128];
    int bid = blockIdx.x;
    int swz = (bid & 7) * 1024 + (bid >> 3);
    int rb = swz & 15, nb = swz >> 4;
    int t = threadIdx.x;
    int w = t >> 6, l = t & 63;
    int wm = w & 1, wn = w >> 1;

    if (t < 128) rowbest[t] = ~0ull;

    fx16 acc00, acc01, acc10, acc11;
#pragma unroll
    for (int p = 0; p < 16; p++) { acc00[p] = 0.f; acc01[p] = 0.f; acc10[p] = 0.f; acc11[p] = 0.f; }

    const unsigned short* Abase = Ah + (size_t)(rb * 128) * CC;
    const unsigned short* Bbase = REGB ? nullptr : (Bh + (size_t)(nb * 128) * CC);
    const float* Bfbase = Bf + (size_t)(nb * 128) * CC;

    for (int kt = 0; kt < 6; kt++) {
        int k0 = kt * 64;
#pragma unroll
        for (int q = 0; q < 4; q++) {
            int c = q * 256 + t;
            int r = c & 127, g = c >> 7;
            gl_lds16(Abase + (size_t)r * CC + k0 + g * 8, &As[g][r]);
            if (!REGB) {
                gl_lds16(Bbase + (size_t)r * CC + k0 + g * 8, &Bs[g][r]);
            } else {
                const float* src = Bfbase + (size_t)r * CC + k0 + g * 8;
                float4 v0 = *(const float4*)(src);
                float4 v1 = *(const float4*)(src + 4);
                unsigned short tmp[8];
                tmp[0] = f2bf_rne(v0.x); tmp[1] = f2bf_rne(v0.y);
                tmp[2] = f2bf_rne(v0.z); tmp[3] = f2bf_rne(v0.w);
                tmp[4] = f2bf_rne(v1.x); tmp[5] = f2bf_rne(v1.y);
                tmp[6] = f2bf_rne(v1.z); tmp[7] = f2bf_rne(v1.w);
                Bs[g][r] = *(const bf16x8*)tmp;
            }
        }
        __syncthreads();
#pragma unroll
        for (int s = 0; s < 4; s++) {
            int g = s * 2 + (l >> 5);
            bf16x8 a0 = As[g][wm * 64 + (l & 31)];
            bf16x8 a1 = As[g][wm * 64 + 32 + (l & 31)];
            bf16x8 b0 = Bs[g][wn * 64 + (l & 31)];
            bf16x8 b1 = Bs[g][wn * 64 + 32 + (l & 31)];
            acc00 = __builtin_amdgcn_mfma_f32_32x32x16_bf16(a0, b0, acc00, 0, 0, 0);
            acc01 = __builtin_amdgcn_mfma_f32_32x32x16_bf16(a0, b1, acc01, 0, 0, 0);
            acc10 = __builtin_amdgcn_mfma_f32_32x32x16_bf16(a1, b0, acc10, 0, 0, 0);
            acc11 = __builtin_amdgcn_mfma_f32_32x32x16_bf16(a1, b1, acc11, 0, 0, 0);
        }
        __syncthreads();
    }

    int colg0 = nb * 128 + wn * 64 + (l & 31);
    int colg1 = colg0 + 32;
    float yn0 = yn[colg0], yn1 = yn[colg1];
#pragma unroll
    for (int i = 0; i < 2; i++) {
#pragma unroll
        for (int p = 0; p < 16; p++) {
            float a0v = (i == 0) ? acc00[p] : acc10[p];
            float a1v = (i == 0) ? acc01[p] : acc11[p];
            int rl = i * 32 + (p & 3) + 8 * (p >> 2) + 4 * (l >> 5);
            int grow = rb * 128 + wm * 64 + rl;
            float xr = xn[grow];
            float d0 = fmaxf(xr - 2.f * a0v + yn0, 0.f);
            float d1 = fmaxf(xr - 2.f * a1v + yn1, 0.f);
            unsigned long long k0 = ((unsigned long long)__float_as_uint(d0) << 32) | (unsigned)colg0;
            unsigned long long k1 = ((unsigned long long)__float_as_uint(d1) << 32) | (unsigned)colg1;
            unsigned long long best = k0 < k1 ? k0 : k1;
#pragma unroll
            for (int m = 1; m < 32; m <<= 1) {
                unsigned long long o2 = __shfl_xor(best, m);
                if (o2 < best) best = o2;
            }
            if ((l & 31) == 0) atomicMin(&rowbest[wm * 64 + rl], best);
        }
    }
    __syncthreads();
    if (t < 128) partials[(size_t)nb * GM + rb * 128 + t] = rowbest[t];
}

// ---------------- K6/K7: two-stage min reduction ----------------
__global__ void k_reduce1(const unsigned long long* __restrict__ partials,
                          unsigned long long* __restrict__ partial2) {
    int row = blockIdx.x * 256 + threadIdx.x;
    int ng = blockIdx.y;
    unsigned long long m = ~0ull;
    for (int n = 0; n < 64; n++) {
        unsigned long long v = partials[(size_t)(ng * 64 + n) * GM + row];
        if (v < m) m = v;
    }
    partial2[ng * GM + row] = m;
}

__global__ void k_reduce2(const unsigned long long* __restrict__ partial2,
                          float* __restrict__ scores, int* __restrict__ locs) {
    int row = blockIdx.x * 256 + threadIdx.x;
    unsigned long long m = ~0ull;
    for (int g = 0; g < 8; g++) {
        unsigned long long v = partial2[g * GM + row];
        if (v < m) m = v;
    }
    scores[row] = sqrtf(__uint_as_float((unsigned)(m >> 32)));
    locs[row] = (int)(m & 0xffffffffu);
}

// ---------------- K8: per-batch top-4 candidates ----------------
__global__ void k_cand(const float* __restrict__ scores, int* __restrict__ cand) {
    __shared__ unsigned long long key[256];
    __shared__ unsigned long long red[256];
    int b = blockIdx.x, t = threadIdx.x;
    float sc = scores[b * SS + t];
    key[t] = ((unsigned long long)__float_as_uint(sc) << 32) | (unsigned)(255 - t);
    __syncthreads();
    for (int k = 0; k < 4; k++) {
        red[t] = key[t];
        __syncthreads();
        for (int s = 128; s; s >>= 1) {
            if (t < s && red[t + s] > red[t]) red[t] = red[t + s];
            __syncthreads();
        }
        unsigned long long win = red[0];
        int patch = 255 - (int)(win & 0xffffffffu);
        if (t == 0) cand[b * 4 + k] = b * SS + patch;
        __syncthreads();
        if (t == patch) key[t] = 0;
        __syncthreads();
    }
}

// ---------------- K9: exact fp32 re-search for 32 candidate rows ----------------
#define RF_ROWS 8
__global__ __launch_bounds__(256) void k_refine(
        const float* __restrict__ emb, const float* __restrict__ mb,
        const float* __restrict__ xn, const float* __restrict__ yn,
        const int* __restrict__ cand, unsigned long long* __restrict__ refpart) {
    __shared__ float cl[32 * CC];
    __shared__ float xnc[32];
    __shared__ int cr[32];
    __shared__ unsigned long long bmin[32];
    int t = threadIdx.x;
    if (t < 32) cr[t] = cand[t];
    __syncthreads();
    if (t < 32) { xnc[t] = xn[cr[t]]; bmin[t] = ~0ull; }
    for (int i = t; i < 32 * CC; i += 256) {
        int j = i / CC, p = i - j * CC;
        cl[i] = emb[(size_t)cr[j] * CC + p];
    }
    __syncthreads();
    int w = t >> 6, l = t & 63;
    int m0 = blockIdx.x * RF_ROWS + w * 2, m1 = m0 + 1;
    float2 r0[3], r1[3];
#pragma unroll
    for (int c = 0; c < 3; c++) {
        r0[c] = *(const float2*)&mb[(size_t)m0 * CC + c * 128 + l * 2];
        r1[c] = *(const float2*)&mb[(size_t)m1 * CC + c * 128 + l * 2];
    }
    float ya = yn[m0], yb = yn[m1];
    for (int j = 0; j < 32; j++) {
        float s0 = 0.f, s1 = 0.f;
#pragma unroll
        for (int c = 0; c < 3; c++) {
            float2 cv = *(const float2*)&cl[j * CC + c * 128 + l * 2];
            s0 = fmaf(r0[c].x, cv.x, s0); s0 = fmaf(r0[c].y, cv.y, s0);
            s1 = fmaf(r1[c].x, cv.x, s1); s1 = fmaf(r1[c].y, cv.y, s1);
        }
#pragma unroll
        for (int mm = 32; mm; mm >>= 1) { s0 += __shfl_xor(s0, mm); s1 += __shfl_xor(s1, mm); }
        if (l == 0) {
            float d0 = fmaxf(xnc[j] - 2.f * s0 + ya, 0.f);
            float d1 = fmaxf(xnc[j] - 2.f * s1 + yb, 0.f);
            unsigned long long k0 = ((unsigned long long)__float_as_uint(d0) << 32) | (unsigned)m0;
            unsigned long long k1 = ((unsigned long long)__float_as_uint(d1) << 32) | (unsigned)m1;
            unsigned long long kb = k0 < k1 ? k0 : k1;
            atomicMin(&bmin[j], kb);
        }
    }
    __syncthreads();
    if (t < 32) refpart[(size_t)blockIdx.x * 32 + t] = bmin[t];
}

__global__ void k_refred(const unsigned long long* __restrict__ refpart,
                         unsigned long long* __restrict__ keys2) {
    __shared__ unsigned long long red[256];
    int j = blockIdx.x, t = threadIdx.x;
    unsigned long long m = ~0ull;
    for (int i = t; i < MM / RF_ROWS; i += 256) {
        unsigned long long v = refpart[(size_t)i * 32 + j];
        if (v < m) m = v;
    }
    red[t] = m;
    __syncthreads();
    for (int s = 128; s; s >>= 1) {
        if (t < s && red[t + s] < red[t]) red[t] = red[t + s];
        __syncthreads();
    }
    if (t == 0) keys2[j] = red[0];
}

__global__ void k_final(const unsigned long long* __restrict__ keys2, const int* __restrict__ cand,
                        int* __restrict__ mp, float* __restrict__ scb, int* __restrict__ nn) {
    int b = threadIdx.x;
    if (b < BB) {
        float bestsc = -1.f;
        int bestpatch = 1 << 20, bestnn = 0;
        for (int k = 0; k < 4; k++) {
            unsigned long long key = keys2[b * 4 + k];
            float sc = sqrtf(__uint_as_float((unsigned)(key >> 32)));
            int patch = cand[b * 4 + k] & 255;
            int nnidx = (int)(key & 0xffffffffu);
            if (sc > bestsc || (sc == bestsc && patch < bestpatch)) {
                bestsc = sc; bestpatch = patch; bestnn = nnidx;
            }
        }
        mp[b] = bestpatch; scb[b] = bestsc; nn[b] = bestnn;
    }
}

// ---------------- K12: d_nn ----------------
__global__ void k_dnn(const float* __restrict__ mb, const float* __restrict__ yn,
                      const int* __restrict__ nn, float* __restrict__ dnn) {
    __shared__ float nnf[BB][CC];
    int t = threadIdx.x;
    for (int i = t; i < BB * CC; i += 256) {
        int bb = i / CC, cc = i % CC;
        nnf[bb][cc] = mb[(size_t)nn[bb] * CC + cc];
    }
    __syncthreads();
    int w = t >> 6, l = t & 63;
    int m = blockIdx.x * 4 + w;
    float accv[BB];
#pragma unroll
    for (int b = 0; b < BB; b++) accv[b] = 0.f;
    const float* r = mb + (size_t)m * CC;
#pragma unroll
    for (int i = 0; i < 6; i++) {
        float v = r[i * 64 + l];
#pragma unroll
        for (int b = 0; b < BB; b++) accv[b] = fmaf(v, nnf[b][i * 64 + l], accv[b]);
    }
#pragma unroll
    for (int b = 0; b < BB; b++) {
        float s = accv[b];
#pragma unroll
        for (int mm = 32; mm; mm >>= 1) s += __shfl_xor(s, mm);
        if (l == 0) {
            float d2 = fmaxf(yn[nn[b]] - 2.f * s + yn[m], 0.f);
            dnn[(size_t)b * MM + m] = sqrtf(d2);
        }
    }
}

// ---------------- K13: top-9 ----------------
__global__ void k_top9(const float* __restrict__ dnn, int* __restrict__ sup) {
    __shared__ float sd[256][TOPK];
    __shared__ int sx[256][TOPK];
    int b = blockIdx.x, t = threadIdx.x;
    float ld[TOPK];
    int li[TOPK];
#pragma unroll
    for (int k = 0; k < TOPK; k++) { ld[k] = INFINITY; li[k] = MM; }
    const float* d = dnn + (size_t)b * MM;
    for (int m = t; m < MM; m += 256) {
        float v = d[m];
        if (v < ld[TOPK - 1] || (v == ld[TOPK - 1] && m < li[TOPK - 1])) {
            int k = TOPK - 1;
            while (k > 0 && (v < ld[k - 1] || (v == ld[k - 1] && m < li[k - 1]))) {
                ld[k] = ld[k - 1]; li[k] = li[k - 1]; k--;
            }
            ld[k] = v; li[k] = m;
        }
    }
    for (int k = 0; k < TOPK; k++) { sd[t][k] = ld[k]; sx[t][k] = li[k]; }
    __syncthreads();
    for (int s = 128; s; s >>= 1) {
        if (t < s) {
            float md[TOPK]; int mi[TOPK];
            int p = 0, q = 0;
            for (int k = 0; k < TOPK; k++) {
                float va = sd[t][p], vb = sd[t + s][q];
                int ia = sx[t][p], ib = sx[t + s][q];
                bool ta = (va < vb) || (va == vb && ia < ib);
                if (ta) { md[k] = va; mi[k] = ia; p++; }
                else    { md[k] = vb; mi[k] = ib; q++; }
            }
            for (int k = 0; k < TOPK; k++) { sd[t][k] = md[k]; sx[t][k] = mi[k]; }
        }
        __syncthreads();
    }
    if (t < TOPK) sup[b * TOPK + t] = sx[0][t];
}

// ---------------- K14: pred_score ----------------
__global__ void k_pred(const float* __restrict__ emb, const float* __restrict__ mb,
                       const float* __restrict__ yn, const float* __restrict__ xn,
                       const int* __restrict__ mp, const float* __restrict__ scb,
                       const int* __restrict__ sup, float* __restrict__ outp) {
    __shared__ float ds[TOPK];
    int b = blockIdx.x;
    int t = threadIdx.x;
    int w = t >> 6, l = t & 63;
    int mpb = mp[b];
    const float* mf = emb + ((size_t)b * SS + mpb) * CC;
    float xr = xn[b * SS + mpb];
    for (int k = w; k < TOPK; k += 4) {
        int sidx = sup[b * TOPK + k];
        const float* sr = mb + (size_t)sidx * CC;
        float s = 0.f;
#pragma unroll
        for (int i = 0; i < 6; i++) s = fmaf(mf[i * 64 + l], sr[i * 64 + l], s);
#pragma unroll
        for (int mm = 32; mm; mm >>= 1) s += __shfl_xor(s, mm);
        if (l == 0) ds[k] = sqrtf(fmaxf(xr - 2.f * s + yn[sidx], 0.f));
    }
    __syncthreads();
    if (t == 0) {
        float mx = ds[0];
        for (int k = 1; k < TOPK; k++) mx = fmaxf(mx, ds[k]);
        float num = expf(ds[0] - mx), den = 0.f;
        for (int k = 0; k < TOPK; k++) den += expf(ds[k] - mx);
        outp[b] = (1.f - num / den) * scb[b];
    }
}

// ---------------- K15: anomaly map scatter ----------------
__global__ void k_map(const float* __restrict__ scores, const int* __restrict__ labels,
                      float* __restrict__ out) {
    size_t i = (size_t)blockIdx.x * 256 + threadIdx.x;
    int b = (int)(i / HWP);
    out[i] = scores[b * SS + labels[i]];
}

extern "C" void kernel_launch(void* const* d_in, const int* in_sizes, int n_in,
                              void* d_out, int out_size, void* d_ws, size_t ws_size,
                              hipStream_t stream) {
    const float* feats  = (const float*)d_in[0];
    const int*   labels = (const int*)d_in[1];
    const float* mb     = (const float*)d_in[2];
    float* out = (float*)d_out;

    char* ws = (char*)d_ws;
    const size_t SZ_MBH   = (size_t)MM * CC * 2;
    const size_t SZ_EMBH  = (size_t)GM * CC * 2;
    const size_t SZ_EMB   = (size_t)GM * CC * 4;
    const size_t SZ_YN    = (size_t)MM * 4;
    const size_t SZ_SMALL = 8192;
    const size_t SZ_P2    = (size_t)8 * GM * 8;
    const size_t SZ_BIG   = (size_t)512 * GM * 8;

    size_t need_full = SZ_MBH + SZ_EMBH + SZ_EMB + SZ_YN + 4 * SZ_SMALL + 2048 + SZ_P2 + SZ_BIG + 512;
    bool lowmem = ws_size < need_full;

    size_t o = 0;
    unsigned short* mbh = nullptr;
    if (!lowmem) { mbh = (unsigned short*)(ws + o); o += SZ_MBH; }
    unsigned short* embh = (unsigned short*)(ws + o); o += SZ_EMBH;
    float* emb = (float*)(ws + o);                    o += SZ_EMB;
    float* yn  = (float*)(ws + o);                    o += SZ_YN;
    float* xn  = (float*)(ws + o);                    o += SZ_SMALL;
    unsigned* cntU = (unsigned*)(ws + o);             o += SZ_SMALL;
    float* scores = (float*)(ws + o);                 o += SZ_SMALL;
    int*   locs   = (int*)(ws + o);                   o += SZ_SMALL;
    int*   cand   = (int*)(ws + o);                   o += 256;
    unsigned long long* keys2 = (unsigned long long*)(ws + o); o += 256;
    int*   mp  = (int*)(ws + o);                      o += 128;
    float* scb = (float*)(ws + o);                    o += 128;
    int*   nn  = (int*)(ws + o);                      o += 128;
    int*   sup = (int*)(ws + o);                      o += 512;
    o = (o + 255) & ~(size_t)255;
    unsigned long long* partial2 = (unsigned long long*)(ws + o); o += SZ_P2;
    char* big = ws + o;
    unsigned long long* partials = (unsigned long long*)big;
    unsigned long long* refpart  = (unsigned long long*)big;   // reused after partials consumed
    float* dnn = (float*)(big + 4194304);

    hipMemsetAsync(emb, 0, SZ_EMB, stream);
    hipMemsetAsync(cntU, 0, (size_t)GM * 4, stream);
    k_counts2<<<dim3(49, BB), 256, 0, stream>>>(labels, cntU);
    k_segsum5<<<dim3(16, 6, BB), 256, 0, stream>>>(feats, labels, emb);
    if (!lowmem) k_cvtmb<<<MM / 4, 256, 0, stream>>>(mb, mbh, yn);
    else         k_ynorm<<<MM / 4, 256, 0, stream>>>(mb, yn);
    k_embfin<<<GM, 64, 0, stream>>>(emb, cntU, xn, embh);

    if (!lowmem)
        k_gemm<false><<<8192, 256, 0, stream>>>(embh, mbh, mb, xn, yn, partials);
    else
        k_gemm<true><<<8192, 256, 0, stream>>>(embh, embh, mb, xn, yn, partials);

    k_reduce1<<<dim3(8, 8), 256, 0, stream>>>(partials, partial2);
    k_reduce2<<<8, 256, 0, stream>>>(partial2, scores, locs);
    k_cand<<<BB, 256, 0, stream>>>(scores, cand);
    k_refine<<<MM / RF_ROWS, 256, 0, stream>>>(emb, mb, xn, yn, cand, refpart);
    k_refred<<<32, 256, 0, stream>>>(refpart, keys2);
    k_final<<<1, 64, 0, stream>>>(keys2, cand, mp, scb, nn);
    k_dnn<<<MM / 4, 256, 0, stream>>>(mb, yn, nn, dnn);
    k_top9<<<BB, 256, 0, stream>>>(dnn, sup);
    k_pred<<<BB, 256, 0, stream>>>(emb, mb, yn, xn, mp, scb, sup, out + (size_t)BB * HWP);
    k_map<<<(BB * HWP) / 256, 256, 0, stream>>>(scores, labels, out);
}

// Round 6
// 1090.373 us; speedup vs baseline: 2.5381x; 1.0397x over previous
//
#include <hip/hip_runtime.h>

#define BB 8
#define CC 384
#define HWP 50176
#define SS 256
#define MM 65536
#define TOPK 9
#define GM 2048          // BB*SS emb rows
#define NKC 16           // K-split blocks for segsum

typedef __attribute__((ext_vector_type(8))) __bf16 bf16x8;
typedef __attribute__((ext_vector_type(16))) float fx16;
typedef __attribute__((ext_vector_type(4))) float f32x4;

__device__ __forceinline__ unsigned short f2bf_rne(float x) {
    unsigned u = __float_as_uint(x);
    unsigned r = (u + 0x7FFFu + ((u >> 16) & 1u)) >> 16;
    return (unsigned short)r;
}

__device__ __forceinline__ bf16x8 pack8(float4 v0, float4 v1) {
    bf16x8 r;
    r[0] = (__bf16)v0.x; r[1] = (__bf16)v0.y; r[2] = (__bf16)v0.z; r[3] = (__bf16)v0.w;
    r[4] = (__bf16)v1.x; r[5] = (__bf16)v1.y; r[6] = (__bf16)v1.z; r[7] = (__bf16)v1.w;
    return r;
}

__device__ __forceinline__ void gl_lds16(const void* g, void* l) {
    auto gp = (const __attribute__((address_space(1))) unsigned int*)g;
    auto lp = (__attribute__((address_space(3))) unsigned int*)l;
    __builtin_amdgcn_global_load_lds(gp, lp, 16, 0, 0);
}

// ---------------- K1: per-batch label counts (parallel) ----------------
__global__ void k_counts2(const int* __restrict__ labels, unsigned* __restrict__ cntU) {
    __shared__ unsigned cnt[SS];
    int kc = blockIdx.x, b = blockIdx.y;   // (49, 8)
    int t = threadIdx.x;
    cnt[t] = 0u;
    __syncthreads();
    int4 lv = ((const int4*)(labels + (size_t)b * HWP + kc * 1024))[t];
    atomicAdd(&cnt[lv.x], 1u);
    atomicAdd(&cnt[lv.y], 1u);
    atomicAdd(&cnt[lv.z], 1u);
    atomicAdd(&cnt[lv.w], 1u);
    __syncthreads();
    if (cnt[t]) atomicAdd(&cntU[b * SS + t], cnt[t]);
}

// ---------------- K2: segment sums as one-hot MFMA GEMM, T14-pipelined ----------------
// grid (kc=NKC, cg=6, b=8); block 256 = 4 waves, wave w owns c-cols [cg*64+w*16, +16).
// Per tile step tt: write regs->LDS (bf16 cvt), prefetch tt+1 into regs, barrier,
// MFMA compute (hides the in-flight loads), barrier. Flush: plain stores to kcpart
// (ATOMIC=false) or atomicAdd into emb (lowmem fallback).
template <bool ATOMIC>
__global__ __launch_bounds__(256) void k_segsum6(const float* __restrict__ feats,
                                                 const int* __restrict__ labels,
                                                 float* __restrict__ outp) {
    __shared__ bf16x8 Bs[8][64];    // 8 KB: Bs[g][c_local] = feats[c][k0+g*8 .. +7]
    __shared__ int labL[64];
    __shared__ unsigned smaskL[2];
    int kc = blockIdx.x, cg = blockIdx.y, b = blockIdx.z;
    int t = threadIdx.x, l = t & 63, w = t >> 6;
    int c0b = cg * 64;
    int c0w = c0b + w * 16;
    int g16 = l >> 4;
    int rowl = l & 15;

    f32x4 acc[16];
#pragma unroll
    for (int j = 0; j < 16; j++) acc[j] = (f32x4){0.f, 0.f, 0.f, 0.f};

    const float* fb = feats + ((size_t)b * CC + c0b) * HWP;
    const int* lbase = labels + (size_t)b * HWP + kc * 3136;

    // per-thread staging slots: ids 2t,2t+1 -> same channel row, 16 consecutive floats
    int id0 = t * 2;
    int cl = id0 >> 3, g0 = id0 & 7;
    const float* tbase = fb + (size_t)cl * HWP + kc * 3136 + g0 * 8;

    // prologue: prefetch tile 0
    float4 ra0 = *(const float4*)(tbase + 0);
    float4 ra1 = *(const float4*)(tbase + 4);
    float4 rb0 = *(const float4*)(tbase + 8);
    float4 rb1 = *(const float4*)(tbase + 12);
    int4 rl4 = (t < 16) ? ((const int4*)lbase)[t] : (int4){0, 0, 0, 0};

    if (t == 0) { smaskL[0] = 0u; smaskL[1] = 0u; }

    for (int tt = 0; tt < 49; tt++) {
        __syncthreads();   // (A) previous compute done; Bs/labL free; smask slot zeroed
        if (t < 16) {
            ((int4*)labL)[t] = rl4;
            unsigned m = (1u << (rl4.x >> 4)) | (1u << (rl4.y >> 4)) |
                         (1u << (rl4.z >> 4)) | (1u << (rl4.w >> 4));
            atomicOr(&smaskL[tt & 1], m);
        }
        Bs[g0][cl] = pack8(ra0, ra1);
        Bs[g0 + 1][cl] = pack8(rb0, rb1);
        if (tt + 1 < 49) {   // issue next-tile loads; latency hidden under compute
            const float* nb_ = tbase + (size_t)(tt + 1) * 64;
            ra0 = *(const float4*)(nb_ + 0);
            ra1 = *(const float4*)(nb_ + 4);
            rb0 = *(const float4*)(nb_ + 8);
            rb1 = *(const float4*)(nb_ + 12);
            if (t < 16) rl4 = ((const int4*)(lbase + (tt + 1) * 64))[t];
        }
        __syncthreads();   // (B) Bs/labL ready
        unsigned sm = __builtin_amdgcn_readfirstlane(smaskL[tt & 1]);
        if (t == 0) smaskL[(tt + 1) & 1] = 0u;   // pre-zero other slot for next iter
        bf16x8 bf0 = Bs[g16][w * 16 + rowl];
        bf16x8 bf1 = Bs[4 + g16][w * 16 + rowl];
        int4 la0 = ((int4*)labL)[g16 * 2 + 0];
        int4 la1 = ((int4*)labL)[g16 * 2 + 1];
        int4 lb0 = ((int4*)labL)[8 + g16 * 2 + 0];
        int4 lb1 = ((int4*)labL)[8 + g16 * 2 + 1];
#pragma unroll
        for (int j = 0; j < 16; j++) {
            if (sm & (1u << j)) {
                int tgt = j * 16 + rowl;
                union { unsigned u[4]; bf16x8 v; } A;
                A.u[0] = (la0.x == tgt ? 0x3F80u : 0u) | (la0.y == tgt ? 0x3F800000u : 0u);
                A.u[1] = (la0.z == tgt ? 0x3F80u : 0u) | (la0.w == tgt ? 0x3F800000u : 0u);
                A.u[2] = (la1.x == tgt ? 0x3F80u : 0u) | (la1.y == tgt ? 0x3F800000u : 0u);
                A.u[3] = (la1.z == tgt ? 0x3F80u : 0u) | (la1.w == tgt ? 0x3F800000u : 0u);
                acc[j] = __builtin_amdgcn_mfma_f32_16x16x32_bf16(A.v, bf0, acc[j], 0, 0, 0);
                A.u[0] = (lb0.x == tgt ? 0x3F80u : 0u) | (lb0.y == tgt ? 0x3F800000u : 0u);
                A.u[1] = (lb0.z == tgt ? 0x3F80u : 0u) | (lb0.w == tgt ? 0x3F800000u : 0u);
                A.u[2] = (lb1.x == tgt ? 0x3F80u : 0u) | (lb1.y == tgt ? 0x3F800000u : 0u);
                A.u[3] = (lb1.z == tgt ? 0x3F80u : 0u) | (lb1.w == tgt ? 0x3F800000u : 0u);
                acc[j] = __builtin_amdgcn_mfma_f32_16x16x32_bf16(A.v, bf1, acc[j], 0, 0, 0);
            }
        }
    }
    // flush: C row = j*16 + g16*4 + r, col = c0w + rowl
    if (ATOMIC) {
#pragma unroll
        for (int j = 0; j < 16; j++)
#pragma unroll
            for (int r = 0; r < 4; r++) {
                float v = acc[j][r];
                if (v != 0.f)
                    atomicAdd(&outp[((size_t)b * SS + j * 16 + g16 * 4 + r) * CC + c0w + rowl], v);
            }
    } else {
        float* dst = outp + (size_t)(kc * BB + b) * SS * CC;
#pragma unroll
        for (int j = 0; j < 16; j++)
#pragma unroll
            for (int r = 0; r < 4; r++)
                dst[(size_t)(j * 16 + g16 * 4 + r) * CC + c0w + rowl] = acc[j][r];
    }
}

// ---------------- K3: bank fp32->bf16 + row norms ----------------
__global__ void k_cvtmb(const float* __restrict__ mb, unsigned short* __restrict__ mbh,
                        float* __restrict__ yn) {
    int w = threadIdx.x >> 6, l = threadIdx.x & 63;
    int row = blockIdx.x * 4 + w;
    const float* r = mb + (size_t)row * CC;
    unsigned short* o = mbh + (size_t)row * CC;
    float s = 0.f;
#pragma unroll
    for (int i = 0; i < 6; i++) {
        float v = r[i * 64 + l];
        s = fmaf(v, v, s);
        o[i * 64 + l] = f2bf_rne(v);
    }
#pragma unroll
    for (int m = 32; m; m >>= 1) s += __shfl_xor(s, m);
    if (l == 0) yn[row] = s;
}

__global__ void k_ynorm(const float* __restrict__ mb, float* __restrict__ yn) {
    int w = threadIdx.x >> 6, l = threadIdx.x & 63;
    int row = blockIdx.x * 4 + w;
    const float* r = mb + (size_t)row * CC;
    float s = 0.f;
#pragma unroll
    for (int i = 0; i < 6; i++) { float v = r[i * 64 + l]; s = fmaf(v, v, s); }
#pragma unroll
    for (int m = 32; m; m >>= 1) s += __shfl_xor(s, m);
    if (l == 0) yn[row] = s;
}

// ---------------- K4a: reduce kc-partials -> emb + norms + bf16 copy ----------------
__global__ void k_embfin2(const float* __restrict__ kcpart, const unsigned* __restrict__ counts,
                          float* __restrict__ emb, float* __restrict__ xn,
                          unsigned short* __restrict__ embh) {
    int i = blockIdx.x;   // b*SS + s
    int b = i >> 8, s256 = i & 255;
    int l = threadIdx.x;  // 64
    float a6[6] = {0.f, 0.f, 0.f, 0.f, 0.f, 0.f};
    for (int kc = 0; kc < NKC; kc++) {
        const float* row = kcpart + ((size_t)(kc * BB + b) * SS + s256) * CC;
#pragma unroll
        for (int j = 0; j < 6; j++) a6[j] += row[j * 64 + l];
    }
    float inv = 1.f / fmaxf((float)counts[i], 1.f);
    float ss = 0.f;
#pragma unroll
    for (int j = 0; j < 6; j++) {
        float v = a6[j] * inv;
        emb[(size_t)i * CC + j * 64 + l] = v;
        embh[(size_t)i * CC + j * 64 + l] = f2bf_rne(v);
        ss = fmaf(v, v, ss);
    }
#pragma unroll
    for (int m = 32; m; m >>= 1) ss += __shfl_xor(ss, m);
    if (l == 0) xn[i] = ss;
}

// ---------------- K4b: finalize emb in place (lowmem path) ----------------
__global__ void k_embfin(float* __restrict__ emb, const unsigned* __restrict__ counts,
                         float* __restrict__ xn, unsigned short* __restrict__ embh) {
    int i = blockIdx.x, l = threadIdx.x;
    float inv = 1.f / fmaxf((float)counts[i], 1.f);
    float* e = emb + (size_t)i * CC;
    unsigned short* o = embh + (size_t)i * CC;
    float s = 0.f;
#pragma unroll
    for (int j = 0; j < 6; j++) {
        float v = e[j * 64 + l] * inv;
        e[j * 64 + l] = v;
        o[j * 64 + l] = f2bf_rne(v);
        s = fmaf(v, v, s);
    }
#pragma unroll
    for (int m = 32; m; m >>= 1) s += __shfl_xor(s, m);
    if (l == 0) xn[i] = s;
}

// ---------------- K5: bf16 MFMA GEMM + fused row-min ----------------
template <bool REGB>
__global__ __launch_bounds__(256) void k_gemm(
        const unsigned short* __restrict__ Ah, const unsigned short* __restrict__ Bh,
        const float* __restrict__ Bf,
        const float* __restrict__ xn, const float* __restrict__ yn,
        unsigned long long* __restrict__ partials) {
    __shared__ bf16x8 As[8][128];
    __shared__ bf16x8 Bs[8][128];
    __shared__ unsigned long long rowbest[128];
    int bid = blockIdx.x;
    int swz = (bid & 7) * 1024 + (bid >> 3);
    int rb = swz & 15, nb = swz >> 4;
    int t = threadIdx.x;
    int w = t >> 6, l = t & 63;
    int wm = w & 1, wn = w >> 1;

    if (t < 128) rowbest[t] = ~0ull;

    fx16 acc00, acc01, acc10, acc11;
#pragma unroll
    for (int p = 0; p < 16; p++) { acc00[p] = 0.f; acc01[p] = 0.f; acc10[p] = 0.f; acc11[p] = 0.f; }

    const unsigned short* Abase = Ah + (size_t)(rb * 128) * CC;
    const unsigned short* Bbase = REGB ? nullptr : (Bh + (size_t)(nb * 128) * CC);
    const float* Bfbase = Bf + (size_t)(nb * 128) * CC;

    for (int kt = 0; kt < 6; kt++) {
        int k0 = kt * 64;
#pragma unroll
        for (int q = 0; q < 4; q++) {
            int c = q * 256 + t;
            int r = c & 127, g = c >> 7;
            gl_lds16(Abase + (size_t)r * CC + k0 + g * 8, &As[g][r]);
            if (!REGB) {
                gl_lds16(Bbase + (size_t)r * CC + k0 + g * 8, &Bs[g][r]);
            } else {
                const float* src = Bfbase + (size_t)r * CC + k0 + g * 8;
                float4 v0 = *(const float4*)(src);
                float4 v1 = *(const float4*)(src + 4);
                Bs[g][r] = pack8(v0, v1);
            }
        }
        __syncthreads();
#pragma unroll
        for (int s = 0; s < 4; s++) {
            int g = s * 2 + (l >> 5);
            bf16x8 a0 = As[g][wm * 64 + (l & 31)];
            bf16x8 a1 = As[g][wm * 64 + 32 + (l & 31)];
            bf16x8 b0 = Bs[g][wn * 64 + (l & 31)];
            bf16x8 b1 = Bs[g][wn * 64 + 32 + (l & 31)];
            acc00 = __builtin_amdgcn_mfma_f32_32x32x16_bf16(a0, b0, acc00, 0, 0, 0);
            acc01 = __builtin_amdgcn_mfma_f32_32x32x16_bf16(a0, b1, acc01, 0, 0, 0);
            acc10 = __builtin_amdgcn_mfma_f32_32x32x16_bf16(a1, b0, acc10, 0, 0, 0);
            acc11 = __builtin_amdgcn_mfma_f32_32x32x16_bf16(a1, b1, acc11, 0, 0, 0);
        }
        __syncthreads();
    }

    int colg0 = nb * 128 + wn * 64 + (l & 31);
    int colg1 = colg0 + 32;
    float yn0 = yn[colg0], yn1 = yn[colg1];
#pragma unroll
    for (int i = 0; i < 2; i++) {
#pragma unroll
        for (int p = 0; p < 16; p++) {
            float a0v = (i == 0) ? acc00[p] : acc10[p];
            float a1v = (i == 0) ? acc01[p] : acc11[p];
            int rl = i * 32 + (p & 3) + 8 * (p >> 2) + 4 * (l >> 5);
            int grow = rb * 128 + wm * 64 + rl;
            float xr = xn[grow];
            float d0 = fmaxf(xr - 2.f * a0v + yn0, 0.f);
            float d1 = fmaxf(xr - 2.f * a1v + yn1, 0.f);
            unsigned long long k0 = ((unsigned long long)__float_as_uint(d0) << 32) | (unsigned)colg0;
            unsigned long long k1 = ((unsigned long long)__float_as_uint(d1) << 32) | (unsigned)colg1;
            unsigned long long best = k0 < k1 ? k0 : k1;
#pragma unroll
            for (int m = 1; m < 32; m <<= 1) {
                unsigned long long o2 = __shfl_xor(best, m);
                if (o2 < best) best = o2;
            }
            if ((l & 31) == 0) atomicMin(&rowbest[wm * 64 + rl], best);
        }
    }
    __syncthreads();
    if (t < 128) partials[(size_t)nb * GM + rb * 128 + t] = rowbest[t];
}

// ---------------- K6/K7: two-stage min reduction ----------------
__global__ void k_reduce1(const unsigned long long* __restrict__ partials,
                          unsigned long long* __restrict__ partial2) {
    int row = blockIdx.x * 256 + threadIdx.x;
    int ng = blockIdx.y;
    unsigned long long m = ~0ull;
    for (int n = 0; n < 64; n++) {
        unsigned long long v = partials[(size_t)(ng * 64 + n) * GM + row];
        if (v < m) m = v;
    }
    partial2[ng * GM + row] = m;
}

__global__ void k_reduce2(const unsigned long long* __restrict__ partial2,
                          float* __restrict__ scores, int* __restrict__ locs) {
    int row = blockIdx.x * 256 + threadIdx.x;
    unsigned long long m = ~0ull;
    for (int g = 0; g < 8; g++) {
        unsigned long long v = partial2[g * GM + row];
        if (v < m) m = v;
    }
    scores[row] = sqrtf(__uint_as_float((unsigned)(m >> 32)));
    locs[row] = (int)(m & 0xffffffffu);
}

// ---------------- K8: per-batch top-4 candidates ----------------
__global__ void k_cand(const float* __restrict__ scores, int* __restrict__ cand) {
    __shared__ unsigned long long key[256];
    __shared__ unsigned long long red[256];
    int b = blockIdx.x, t = threadIdx.x;
    float sc = scores[b * SS + t];
    key[t] = ((unsigned long long)__float_as_uint(sc) << 32) | (unsigned)(255 - t);
    __syncthreads();
    for (int k = 0; k < 4; k++) {
        red[t] = key[t];
        __syncthreads();
        for (int s = 128; s; s >>= 1) {
            if (t < s && red[t + s] > red[t]) red[t] = red[t + s];
            __syncthreads();
        }
        unsigned long long win = red[0];
        int patch = 255 - (int)(win & 0xffffffffu);
        if (t == 0) cand[b * 4 + k] = b * SS + patch;
        __syncthreads();
        if (t == patch) key[t] = 0;
        __syncthreads();
    }
}

// ---------------- K9: exact fp32 re-search for 32 candidate rows ----------------
#define RF_ROWS 8
__global__ __launch_bounds__(256) void k_refine(
        const float* __restrict__ emb, const float* __restrict__ mb,
        const float* __restrict__ xn, const float* __restrict__ yn,
        const int* __restrict__ cand, unsigned long long* __restrict__ refpart) {
    __shared__ float cl[32 * CC];
    __shared__ float xnc[32];
    __shared__ int cr[32];
    __shared__ unsigned long long bmin[32];
    int t = threadIdx.x;
    if (t < 32) cr[t] = cand[t];
    __syncthreads();
    if (t < 32) { xnc[t] = xn[cr[t]]; bmin[t] = ~0ull; }
    for (int i = t; i < 32 * CC; i += 256) {
        int j = i / CC, p = i - j * CC;
        cl[i] = emb[(size_t)cr[j] * CC + p];
    }
    __syncthreads();
    int w = t >> 6, l = t & 63;
    int m0 = blockIdx.x * RF_ROWS + w * 2, m1 = m0 + 1;
    float2 r0[3], r1[3];
#pragma unroll
    for (int c = 0; c < 3; c++) {
        r0[c] = *(const float2*)&mb[(size_t)m0 * CC + c * 128 + l * 2];
        r1[c] = *(const float2*)&mb[(size_t)m1 * CC + c * 128 + l * 2];
    }
    float ya = yn[m0], yb = yn[m1];
    for (int j = 0; j < 32; j++) {
        float s0 = 0.f, s1 = 0.f;
#pragma unroll
        for (int c = 0; c < 3; c++) {
            float2 cv = *(const float2*)&cl[j * CC + c * 128 + l * 2];
            s0 = fmaf(r0[c].x, cv.x, s0); s0 = fmaf(r0[c].y, cv.y, s0);
            s1 = fmaf(r1[c].x, cv.x, s1); s1 = fmaf(r1[c].y, cv.y, s1);
        }
#pragma unroll
        for (int mm = 32; mm; mm >>= 1) { s0 += __shfl_xor(s0, mm); s1 += __shfl_xor(s1, mm); }
        if (l == 0) {
            float d0 = fmaxf(xnc[j] - 2.f * s0 + ya, 0.f);
            float d1 = fmaxf(xnc[j] - 2.f * s1 + yb, 0.f);
            unsigned long long k0 = ((unsigned long long)__float_as_uint(d0) << 32) | (unsigned)m0;
            unsigned long long k1 = ((unsigned long long)__float_as_uint(d1) << 32) | (unsigned)m1;
            unsigned long long kb = k0 < k1 ? k0 : k1;
            atomicMin(&bmin[j], kb);
        }
    }
    __syncthreads();
    if (t < 32) refpart[(size_t)blockIdx.x * 32 + t] = bmin[t];
}

__global__ void k_refred(const unsigned long long* __restrict__ refpart,
                         unsigned long long* __restrict__ keys2) {
    __shared__ unsigned long long red[256];
    int j = blockIdx.x, t = threadIdx.x;
    unsigned long long m = ~0ull;
    for (int i = t; i < MM / RF_ROWS; i += 256) {
        unsigned long long v = refpart[(size_t)i * 32 + j];
        if (v < m) m = v;
    }
    red[t] = m;
    __syncthreads();
    for (int s = 128; s; s >>= 1) {
        if (t < s && red[t + s] < red[t]) red[t] = red[t + s];
        __syncthreads();
    }
    if (t == 0) keys2[j] = red[0];
}

__global__ void k_final(const unsigned long long* __restrict__ keys2, const int* __restrict__ cand,
                        int* __restrict__ mp, float* __restrict__ scb, int* __restrict__ nn) {
    int b = threadIdx.x;
    if (b < BB) {
        float bestsc = -1.f;
        int bestpatch = 1 << 20, bestnn = 0;
        for (int k = 0; k < 4; k++) {
            unsigned long long key = keys2[b * 4 + k];
            float sc = sqrtf(__uint_as_float((unsigned)(key >> 32)));
            int patch = cand[b * 4 + k] & 255;
            int nnidx = (int)(key & 0xffffffffu);
            if (sc > bestsc || (sc == bestsc && patch < bestpatch)) {
                bestsc = sc; bestpatch = patch; bestnn = nnidx;
            }
        }
        mp[b] = bestpatch; scb[b] = bestsc; nn[b] = bestnn;
    }
}

// ---------------- K12: d_nn ----------------
__global__ void k_dnn(const float* __restrict__ mb, const float* __restrict__ yn,
                      const int* __restrict__ nn, float* __restrict__ dnn) {
    __shared__ float nnf[BB][CC];
    int t = threadIdx.x;
    for (int i = t; i < BB * CC; i += 256) {
        int bb = i / CC, cc = i % CC;
        nnf[bb][cc] = mb[(size_t)nn[bb] * CC + cc];
    }
    __syncthreads();
    int w = t >> 6, l = t & 63;
    int m = blockIdx.x * 4 + w;
    float accv[BB];
#pragma unroll
    for (int b = 0; b < BB; b++) accv[b] = 0.f;
    const float* r = mb + (size_t)m * CC;
#pragma unroll
    for (int i = 0; i < 6; i++) {
        float v = r[i * 64 + l];
#pragma unroll
        for (int b = 0; b < BB; b++) accv[b] = fmaf(v, nnf[b][i * 64 + l], accv[b]);
    }
#pragma unroll
    for (int b = 0; b < BB; b++) {
        float s = accv[b];
#pragma unroll
        for (int mm = 32; mm; mm >>= 1) s += __shfl_xor(s, mm);
        if (l == 0) {
            float d2 = fmaxf(yn[nn[b]] - 2.f * s + yn[m], 0.f);
            dnn[(size_t)b * MM + m] = sqrtf(d2);
        }
    }
}

// ---------------- K13: top-9 ----------------
__global__ void k_top9(const float* __restrict__ dnn, int* __restrict__ sup) {
    __shared__ float sd[256][TOPK];
    __shared__ int sx[256][TOPK];
    int b = blockIdx.x, t = threadIdx.x;
    float ld[TOPK];
    int li[TOPK];
#pragma unroll
    for (int k = 0; k < TOPK; k++) { ld[k] = INFINITY; li[k] = MM; }
    const float* d = dnn + (size_t)b * MM;
    for (int m = t; m < MM; m += 256) {
        float v = d[m];
        if (v < ld[TOPK - 1] || (v == ld[TOPK - 1] && m < li[TOPK - 1])) {
            int k = TOPK - 1;
            while (k > 0 && (v < ld[k - 1] || (v == ld[k - 1] && m < li[k - 1]))) {
                ld[k] = ld[k - 1]; li[k] = li[k - 1]; k--;
            }
            ld[k] = v; li[k] = m;
        }
    }
    for (int k = 0; k < TOPK; k++) { sd[t][k] = ld[k]; sx[t][k] = li[k]; }
    __syncthreads();
    for (int s = 128; s; s >>= 1) {
        if (t < s) {
            float md[TOPK]; int mi[TOPK];
            int p = 0, q = 0;
            for (int k = 0; k < TOPK; k++) {
                float va = sd[t][p], vb = sd[t + s][q];
                int ia = sx[t][p], ib = sx[t + s][q];
                bool ta = (va < vb) || (va == vb && ia < ib);
                if (ta) { md[k] = va; mi[k] = ia; p++; }
                else    { md[k] = vb; mi[k] = ib; q++; }
            }
            for (int k = 0; k < TOPK; k++) { sd[t][k] = md[k]; sx[t][k] = mi[k]; }
        }
        __syncthreads();
    }
    if (t < TOPK) sup[b * TOPK + t] = sx[0][t];
}

// ---------------- K14: pred_score ----------------
__global__ void k_pred(const float* __restrict__ emb, const float* __restrict__ mb,
                       const float* __restrict__ yn, const float* __restrict__ xn,
                       const int* __restrict__ mp, const float* __restrict__ scb,
                       const int* __restrict__ sup, float* __restrict__ outp) {
    __shared__ float ds[TOPK];
    int b = blockIdx.x;
    int t = threadIdx.x;
    int w = t >> 6, l = t & 63;
    int mpb = mp[b];
    const float* mf = emb + ((size_t)b * SS + mpb) * CC;
    float xr = xn[b * SS + mpb];
    for (int k = w; k < TOPK; k += 4) {
        int sidx = sup[b * TOPK + k];
        const float* sr = mb + (size_t)sidx * CC;
        float s = 0.f;
#pragma unroll
        for (int i = 0; i < 6; i++) s = fmaf(mf[i * 64 + l], sr[i * 64 + l], s);
#pragma unroll
        for (int mm = 32; mm; mm >>= 1) s += __shfl_xor(s, mm);
        if (l == 0) ds[k] = sqrtf(fmaxf(xr - 2.f * s + yn[sidx], 0.f));
    }
    __syncthreads();
    if (t == 0) {
        float mx = ds[0];
        for (int k = 1; k < TOPK; k++) mx = fmaxf(mx, ds[k]);
        float num = expf(ds[0] - mx), den = 0.f;
        for (int k = 0; k < TOPK; k++) den += expf(ds[k] - mx);
        outp[b] = (1.f - num / den) * scb[b];
    }
}

// ---------------- K15: anomaly map scatter ----------------
__global__ void k_map(const float* __restrict__ scores, const int* __restrict__ labels,
                      float* __restrict__ out) {
    size_t i = (size_t)blockIdx.x * 256 + threadIdx.x;
    int b = (int)(i / HWP);
    out[i] = scores[b * SS + labels[i]];
}

extern "C" void kernel_launch(void* const* d_in, const int* in_sizes, int n_in,
                              void* d_out, int out_size, void* d_ws, size_t ws_size,
                              hipStream_t stream) {
    const float* feats  = (const float*)d_in[0];
    const int*   labels = (const int*)d_in[1];
    const float* mb     = (const float*)d_in[2];
    float* out = (float*)d_out;

    char* ws = (char*)d_ws;
    const size_t SZ_MBH   = (size_t)MM * CC * 2;              // 50.3 MB
    const size_t SZ_EMBH  = (size_t)GM * CC * 2;
    const size_t SZ_EMB   = (size_t)GM * CC * 4;
    const size_t SZ_YN    = (size_t)MM * 4;
    const size_t SZ_SMALL = 8192;
    const size_t SZ_P2    = (size_t)8 * GM * 8;
    const size_t SZ_KCP   = (size_t)NKC * BB * SS * CC * 4;   // 50.3 MB kc-partials
    const size_t SZ_BIG   = SZ_KCP;                           // also holds partials/refpart/dnn later

    size_t need_full = SZ_MBH + SZ_EMBH + SZ_EMB + SZ_YN + 4 * SZ_SMALL + 2048 + SZ_P2 + SZ_BIG + 512;
    bool lowmem = ws_size < need_full;

    size_t o = 0;
    unsigned short* mbh = nullptr;
    if (!lowmem) { mbh = (unsigned short*)(ws + o); o += SZ_MBH; }
    unsigned short* embh = (unsigned short*)(ws + o); o += SZ_EMBH;
    float* emb = (float*)(ws + o);                    o += SZ_EMB;
    float* yn  = (float*)(ws + o);                    o += SZ_YN;
    float* xn  = (float*)(ws + o);                    o += SZ_SMALL;
    unsigned* cntU = (unsigned*)(ws + o);             o += SZ_SMALL;
    float* scores = (float*)(ws + o);                 o += SZ_SMALL;
    int*   locs   = (int*)(ws + o);                   o += SZ_SMALL;
    int*   cand   = (int*)(ws + o);                   o += 256;
    unsigned long long* keys2 = (unsigned long long*)(ws + o); o += 256;
    int*   mp  = (int*)(ws + o);                      o += 128;
    float* scb = (float*)(ws + o);                    o += 128;
    int*   nn  = (int*)(ws + o);                      o += 128;
    int*   sup = (int*)(ws + o);                      o += 512;
    o = (o + 255) & ~(size_t)255;
    unsigned long long* partial2 = (unsigned long long*)(ws + o); o += SZ_P2;
    char* big = ws + o;
    float* kcpart = (float*)big;                                   // segsum partials (consumed by embfin2)
    unsigned long long* partials = (unsigned long long*)big;       // gemm partials (after kcpart dead)
    unsigned long long* refpart  = (unsigned long long*)big;       // after partials consumed
    float* dnn = (float*)(big + 4194304);                          // disjoint from refpart

    hipMemsetAsync(cntU, 0, (size_t)GM * 4, stream);
    k_counts2<<<dim3(49, BB), 256, 0, stream>>>(labels, cntU);

    if (!lowmem) {
        k_segsum6<false><<<dim3(NKC, 6, BB), 256, 0, stream>>>(feats, labels, kcpart);
        k_cvtmb<<<MM / 4, 256, 0, stream>>>(mb, mbh, yn);
        k_embfin2<<<GM, 64, 0, stream>>>(kcpart, cntU, emb, xn, embh);
        k_gemm<false><<<8192, 256, 0, stream>>>(embh, mbh, mb, xn, yn, partials);
    } else {
        hipMemsetAsync(emb, 0, SZ_EMB, stream);
        k_segsum6<true><<<dim3(NKC, 6, BB), 256, 0, stream>>>(feats, labels, emb);
        k_ynorm<<<MM / 4, 256, 0, stream>>>(mb, yn);
        k_embfin<<<GM, 64, 0, stream>>>(emb, cntU, xn, embh);
        k_gemm<true><<<8192, 256, 0, stream>>>(embh, embh, mb, xn, yn, partials);
    }

    k_reduce1<<<dim3(8, 8), 256, 0, stream>>>(partials, partial2);
    k_reduce2<<<8, 256, 0, stream>>>(partial2, scores, locs);
    k_cand<<<BB, 256, 0, stream>>>(scores, cand);
    k_refine<<<MM / RF_ROWS, 256, 0, stream>>>(emb, mb, xn, yn, cand, refpart);
    k_refred<<<32, 256, 0, stream>>>(refpart, keys2);
    k_final<<<1, 64, 0, stream>>>(keys2, cand, mp, scb, nn);
    k_dnn<<<MM / 4, 256, 0, stream>>>(mb, yn, nn, dnn);
    k_top9<<<BB, 256, 0, stream>>>(dnn, sup);
    k_pred<<<BB, 256, 0, stream>>>(emb, mb, yn, xn, mp, scb, sup, out + (size_t)BB * HWP);
    k_map<<<(BB * HWP) / 256, 256, 0, stream>>>(scores, labels, out);
}